// Round 6
// baseline (393.027 us; speedup 1.0000x reference)
//
#include <hip/hip_runtime.h>

#define B_    64
#define C_    256
#define H_    56
#define W_    56
#define N_    6890
#define HW_   3136
#define NTILE 108          // ceil(6890/64) point tiles

#define WB1_OFF (128*256)
#define WB2_OFF (128*256 + 64*384)
#define WTOT    (128*256 + 64*384 + 5*320)   // 58944 bf16 weight elements

typedef __attribute__((ext_vector_type(8))) __bf16 bf16x8;
typedef __attribute__((ext_vector_type(8))) unsigned short ushort8;
typedef __attribute__((ext_vector_type(4))) float f32x4;
typedef __attribute__((ext_vector_type(2))) float f32x2;
typedef __attribute__((ext_vector_type(4))) unsigned int uint4v;
typedef __attribute__((ext_vector_type(2))) unsigned int uint2v;

__device__ __forceinline__ unsigned short f2bf(float f) {
    unsigned int u = __builtin_bit_cast(unsigned int, f);
    u += 0x7FFFu + ((u >> 16) & 1u);   // RTNE
    return (unsigned short)(u >> 16);
}
__device__ __forceinline__ unsigned int pack2(float lo, float hi) {
    return (unsigned int)f2bf(lo) | ((unsigned int)f2bf(hi) << 16);
}
__device__ __forceinline__ float leaky(float v) { return v > 0.f ? v : 0.01f * v; }
__device__ __forceinline__ int pswz(int p) { return p ^ ((p >> 3) & 7); }

// ============================ kernel 0: weight bf16 pack ============================
__global__ void wconv_kernel(const float* __restrict__ w0, const float* __restrict__ w1,
                             const float* __restrict__ w2, unsigned short* __restrict__ wb) {
    int i = blockIdx.x * 256 + threadIdx.x;
    if (i >= WTOT) return;
    float v = (i < WB1_OFF) ? w0[i] : (i < WB2_OFF) ? w1[i - WB1_OFF] : w2[i - WB2_OFF];
    wb[i] = f2bf(v);
}

// ======================= kernel T: image transpose to [pix][ch] =====================
// im [b][c][pix] -> imT [b][pix][c] fp32. 64x64 tiles, fully coalesced both sides.
__global__ __launch_bounds__(256) void transpose_kernel(
    const float* __restrict__ im, float* __restrict__ imT) {
    __shared__ float Lt[64][68];
    const int t   = threadIdx.x;
    const int bid = blockIdx.x;
    const int xcd  = bid & 7;
    const int rest = bid >> 3;               // 0..1567
    const int b    = ((rest & 7) << 3) + xcd;
    const int tl   = rest >> 3;              // 0..195
    const int pt   = tl % 49, ct = tl / 49;  // 49 pix-tiles x 4 ch-tiles
    const int p0   = pt * 64, c0 = ct * 64;

    const float* src = im + ((size_t)b * C_ + c0) * HW_ + p0;
#pragma unroll
    for (int rr = 0; rr < 4; rr++) {
        int c_loc = (t >> 4) + rr * 16;
        int pq    = (t & 15) << 2;
        f32x4 v = *(const f32x4*)(src + (size_t)c_loc * HW_ + pq);
        Lt[c_loc][pq]     = v[0];
        Lt[c_loc][pq + 1] = v[1];
        Lt[c_loc][pq + 2] = v[2];
        Lt[c_loc][pq + 3] = v[3];
    }
    __syncthreads();
    float* dst = imT + ((size_t)b * HW_ + p0) * C_ + c0;
#pragma unroll
    for (int i = 0; i < 4; i++) {
        int idx = t + (i << 8);              // 0..1023
        int pr  = idx >> 4;                  // pix row 0..63
        int c4  = (idx & 15) << 2;           // ch quad base
        f32x4 v;
        v[0] = Lt[c4][pr]; v[1] = Lt[c4 + 1][pr];
        v[2] = Lt[c4 + 2][pr]; v[3] = Lt[c4 + 3][pr];
        *(f32x4*)(dst + (size_t)pr * C_ + c4) = v;
    }
}

// ==================== kernel F: fused bilinear sample + MFMA MLP ====================
// B-fragment from swizzled LDS: buf[n][cd ^ ((n&7)<<2)], 4 dwords at k0
__device__ __forceinline__ bf16x8 bfrag(const unsigned int* buf, int rowstride_dw,
                                        int n, int k0) {
    int cd = (k0 >> 1) ^ ((n & 7) << 2);
    uint4v v = *(const uint4v*)(buf + n * rowstride_dw + cd);
    return __builtin_bit_cast(bf16x8, v);
}
__device__ __forceinline__ bf16x8 afrag_bf(const unsigned short* __restrict__ wb, int ldk,
                                           int rowbase, int k0, int lane, int nrows) {
    int i = rowbase + (lane & 15);
    int k = k0 + ((lane >> 4) << 3);
    if (i < nrows) return __builtin_bit_cast(bf16x8, *(const ushort8*)(wb + (size_t)i * ldk + k));
    ushort8 z = {0, 0, 0, 0, 0, 0, 0, 0};
    return __builtin_bit_cast(bf16x8, z);
}

__global__ __launch_bounds__(256, 2) void fused_kernel(
    const float* __restrict__ points, const float* __restrict__ imT,
    const float* __restrict__ b0_, const float* __restrict__ b1,
    const float* __restrict__ b2, const unsigned short* __restrict__ wb,
    float* __restrict__ out0, float* __restrict__ out1) {
    __shared__ float Ls[16384];        // 64KB: Xf [64 rows][64 quads, ^row&7]; later Xs(32K)+Y0(16K)
    __shared__ float Pw[64][4];
    __shared__ int   Pi[64][2];

    const int t    = threadIdx.x;
    const int lane = t & 63;
    const int wave = t >> 6;
    const int bid  = blockIdx.x;
    const int xcd  = bid & 7;                // batch pinned to one XCD -> imT L2-resident
    const int rr   = bid >> 3;
    const int tile = rr % NTILE;
    const int b    = (rr / NTILE) * 8 + xcd;
    const int n0   = tile * 64;

    // ---- per-point bilinear params -> LDS ----
    if (t < 64) {
        int n = min(n0 + t, N_ - 1);
        f32x2 pt = *(const f32x2*)(points + ((size_t)b * N_ + n) * 2);
        float fx = fminf(fmaxf((pt.x + 1.f) * 27.5f, 0.f), 55.f);
        float fy = fminf(fmaxf((pt.y + 1.f) * 27.5f, 0.f), 55.f);
        float x0f = floorf(fx), y0f = floorf(fy);
        int x0 = (int)x0f, y0 = (int)y0f;
        float wx1 = fx - x0f, wy1 = fy - y0f;
        float wx0 = 1.f - wx1, wy0 = 1.f - wy1;
        bool hix = x0 >= W_ - 1;
        int   xb  = hix ? W_ - 2 : x0;
        float wxl = hix ? 0.f : wx0;
        float wxr = hix ? wx0 : wx1;
        int y0c = min(y0, H_ - 1);
        int y1c = min(y0 + 1, H_ - 1);
        Pw[t][0] = wy0 * wxl; Pw[t][1] = wy0 * wxr;
        Pw[t][2] = wy1 * wxl; Pw[t][3] = wy1 * wxr;
        Pi[t][0] = y0c * W_ + xb; Pi[t][1] = y1c * W_ + xb;
    }
    __syncthreads();

    // ---- phase A: cooperative sampling; wave w -> points [16w,16w+16) ----
    const float* ib = imT + (size_t)b * HW_ * C_;
#pragma unroll
    for (int i = 0; i < 16; i += 2) {
        int pA = wave * 16 + i, pB = pA + 1;
        float wA0 = Pw[pA][0], wA1 = Pw[pA][1], wA2 = Pw[pA][2], wA3 = Pw[pA][3];
        float wB0 = Pw[pB][0], wB1 = Pw[pB][1], wB2 = Pw[pB][2], wB3 = Pw[pB][3];
        int aA0 = Pi[pA][0], aA1 = Pi[pA][1];
        int aB0 = Pi[pB][0], aB1 = Pi[pB][1];
        const float* sA0 = ib + ((size_t)aA0 << 8) + (lane << 2);
        const float* sA1 = ib + ((size_t)aA1 << 8) + (lane << 2);
        const float* sB0 = ib + ((size_t)aB0 << 8) + (lane << 2);
        const float* sB1 = ib + ((size_t)aB1 << 8) + (lane << 2);
        f32x4 cA00 = *(const f32x4*)(sA0);
        f32x4 cA01 = *(const f32x4*)(sA0 + 256);
        f32x4 cA10 = *(const f32x4*)(sA1);
        f32x4 cA11 = *(const f32x4*)(sA1 + 256);
        f32x4 cB00 = *(const f32x4*)(sB0);
        f32x4 cB01 = *(const f32x4*)(sB0 + 256);
        f32x4 cB10 = *(const f32x4*)(sB1);
        f32x4 cB11 = *(const f32x4*)(sB1 + 256);
        f32x4 vA, vB;
#pragma unroll
        for (int j = 0; j < 4; j++) {
            vA[j] = wA0 * cA00[j] + wA1 * cA01[j] + wA2 * cA10[j] + wA3 * cA11[j];
            vB[j] = wB0 * cB00[j] + wB1 * cB01[j] + wB2 * cB10[j] + wB3 * cB11[j];
        }
        *(f32x4*)(Ls + pA * 256 + ((lane ^ (pA & 7)) << 2)) = vA;
        *(f32x4*)(Ls + pB * 256 + ((lane ^ (pB & 7)) << 2)) = vB;
    }
    __syncthreads();

    // ---- phase B1: transpose-read Xf to regs (row = lane, quads 16w..16w+15) ----
    f32x4 xr[16];
#pragma unroll
    for (int q = 0; q < 16; q++) {
        int qd = (wave * 16 + q) ^ (lane & 7);
        xr[q] = *(const f32x4*)(Ls + lane * 256 + (qd << 2));
    }
    __syncthreads();

    // ---- phase B2: pf fp32 out (coalesced over n) + bf16 Xs into LDS (aliases Xf) ----
    unsigned int* Xs  = (unsigned int*)Ls;          // [64][128] dwords, 32KB
    unsigned int* Y0s = (unsigned int*)Ls + 8192;   // [64][64]  dwords, 16KB
    {
        float* pfb = out1 + (size_t)b * C_ * N_ + n0;
        const bool okn = (n0 + lane) < N_;
        const int swz = (lane & 7) << 2;
#pragma unroll
        for (int q = 0; q < 16; q += 2) {
            int c0 = wave * 64 + q * 4;
            if (okn) {
#pragma unroll
                for (int jj = 0; jj < 4; jj++) {
                    pfb[(size_t)(c0 + jj) * N_ + lane]     = xr[q][jj];
                    pfb[(size_t)(c0 + 4 + jj) * N_ + lane] = xr[q + 1][jj];
                }
            }
            uint4v pk;
            pk[0] = pack2(xr[q][0], xr[q][1]);     pk[1] = pack2(xr[q][2], xr[q][3]);
            pk[2] = pack2(xr[q + 1][0], xr[q + 1][1]); pk[3] = pack2(xr[q + 1][2], xr[q + 1][3]);
            *(uint4v*)(Xs + lane * 128 + ((c0 >> 1) ^ swz)) = pk;
        }
    }

    // ---- layer 1 A preload ----
    bf16x8 a1[2][8];
#pragma unroll
    for (int mt = 0; mt < 2; mt++)
#pragma unroll
        for (int ks = 0; ks < 8; ks++)
            a1[mt][ks] = afrag_bf(wb, 256, (wave * 2 + mt) * 16, ks * 32, lane, 1 << 30);

    __syncthreads();

    const int cl = lane & 15;
    const int rh = lane >> 4;
    const int kq = rh << 3;

    // ---- layer 1: Y0[128,64] = leaky(W0 @ X + b0) ----
    f32x4 acc1[2][4] = {};
#pragma unroll
    for (int ks = 0; ks < 8; ks++) {
        bf16x8 bx[4];
#pragma unroll
        for (int nt = 0; nt < 4; nt++)
            bx[nt] = bfrag(Xs, 128, nt * 16 + cl, ks * 32 + kq);
#pragma unroll
        for (int mt = 0; mt < 2; mt++)
#pragma unroll
            for (int nt = 0; nt < 4; nt++)
                acc1[mt][nt] = __builtin_amdgcn_mfma_f32_16x16x32_bf16(
                    a1[mt][ks], bx[nt], acc1[mt][nt], 0, 0, 0);
    }

#pragma unroll
    for (int mt = 0; mt < 2; mt++) {
        int m0 = (wave * 2 + mt) * 16 + (rh << 2);
        f32x4 bias = *(const f32x4*)(b0_ + m0);
#pragma unroll
        for (int nt = 0; nt < 4; nt++) {
            int nn = nt * 16 + cl;
            float v0 = leaky(acc1[mt][nt][0] + bias[0]);
            float v1 = leaky(acc1[mt][nt][1] + bias[1]);
            float v2 = leaky(acc1[mt][nt][2] + bias[2]);
            float v3 = leaky(acc1[mt][nt][3] + bias[3]);
            int md = (m0 >> 1) ^ ((nn & 7) << 2);
            uint2v pk; pk[0] = pack2(v0, v1); pk[1] = pack2(v2, v3);
            *(uint2v*)(Y0s + nn * 64 + md) = pk;
        }
    }

    // ---- layer 2 A preload: K = 384 = [Y0(128) | X(256)] ----
    bf16x8 a2[12];
#pragma unroll
    for (int ks = 0; ks < 12; ks++)
        a2[ks] = afrag_bf(wb + WB1_OFF, 384, wave * 16, ks * 32, lane, 1 << 30);

    __syncthreads();

    f32x4 acc2[4] = {};
#pragma unroll
    for (int ks = 0; ks < 12; ks++) {
#pragma unroll
        for (int nt = 0; nt < 4; nt++) {
            bf16x8 bx = (ks < 4) ? bfrag(Y0s, 64, nt * 16 + cl, ks * 32 + kq)
                                 : bfrag(Xs, 128, nt * 16 + cl, (ks - 4) * 32 + kq);
            acc2[nt] = __builtin_amdgcn_mfma_f32_16x16x32_bf16(a2[ks], bx, acc2[nt], 0, 0, 0);
        }
    }

    // layer 3 A preload (W2 zero-padded to 16 rows); K = 320 = [Y1(64) | X(256)]
    bf16x8 a3[10];
#pragma unroll
    for (int ks = 0; ks < 10; ks++)
        a3[ks] = afrag_bf(wb + WB2_OFF, 320, 0, ks * 32, lane, 5);

    __syncthreads();   // all waves done READING Y0s before Y1 overwrites it

    // ---- epilogue 2 -> Y1 (aliases Y0s) ----
    {
        int m0 = wave * 16 + (rh << 2);
        f32x4 bias = *(const f32x4*)(b1 + m0);
#pragma unroll
        for (int nt = 0; nt < 4; nt++) {
            int nn = nt * 16 + cl;
            float v0 = leaky(acc2[nt][0] + bias[0]);
            float v1 = leaky(acc2[nt][1] + bias[1]);
            float v2 = leaky(acc2[nt][2] + bias[2]);
            float v3 = leaky(acc2[nt][3] + bias[3]);
            int md = (m0 >> 1) ^ ((nn & 7) << 2);
            uint2v pk; pk[0] = pack2(v0, v1); pk[1] = pack2(v2, v3);
            *(uint2v*)(Y0s + nn * 32 + md) = pk;   // Y1 layout: [n][32 dwords]
        }
    }

    __syncthreads();

    // ---- layer 3: each wave owns one 16-col N-tile ----
    {
        int nn = wave * 16 + cl;
        f32x4 acc3 = {};
#pragma unroll
        for (int ks = 0; ks < 10; ks++) {
            bf16x8 bx = (ks < 2) ? bfrag(Y0s, 32, nn, ks * 32 + kq)
                                 : bfrag(Xs, 128, nn, (ks - 2) * 32 + kq);
            acc3 = __builtin_amdgcn_mfma_f32_16x16x32_bf16(a3[ks], bx, acc3, 0, 0, 0);
        }
        int gn2 = n0 + nn;
        if (gn2 < N_) {
#pragma unroll
            for (int r2 = 0; r2 < 4; r2++) {
                int m = (rh << 2) + r2;
                if (m < 5) {
                    float v = acc3[r2] + b2[m];
                    v = v > 0.f ? v : 0.f;
                    out0[((size_t)b * 5 + m) * N_ + gn2] = v;
                }
            }
        }
    }
}

// ===================== fallback path (round-4): gather + mlp ========================
__global__ __launch_bounds__(512, 6) void gather_kernel(
    const float* __restrict__ points, const float* __restrict__ im,
    float* __restrict__ out1) {
    __shared__ float Lg[HW_ * 4];
    const int t   = threadIdx.x;
    const int bid = blockIdx.x;
    const int b  = ((bid & 7) << 3) | ((bid >> 3) & 7);
    const int ch = bid >> 6;
    const f32x4* im4 = (const f32x4*)(im + ((size_t)b * C_ + ch * 4) * HW_);
#pragma unroll
    for (int g0 = 0; g0 < 2; g0++) {
        int g = t + (g0 << 9);
        if (g < 784) {
            f32x4 r0 = im4[g], r1 = im4[784 + g], r2 = im4[1568 + g], r3 = im4[2352 + g];
#pragma unroll
            for (int i = 0; i < 4; i++) {
                f32x4 v; v[0] = r0[i]; v[1] = r1[i]; v[2] = r2[i]; v[3] = r3[i];
                *(f32x4*)(Lg + (pswz((g << 2) + i) << 2)) = v;
            }
        }
    }
    __syncthreads();
    const float* ptb = points + (size_t)b * N_ * 2;
    const size_t ob0 = ((size_t)b * C_ + ch * 4) * N_;
#pragma unroll 2
    for (int p = 0; p < 14; p++) {
        int n = t + (p << 9);
        if (n < N_) {
            f32x2 pt = *(const f32x2*)(ptb + 2 * n);
            float fx = fminf(fmaxf((pt.x + 1.f) * 27.5f, 0.f), 55.f);
            float fy = fminf(fmaxf((pt.y + 1.f) * 27.5f, 0.f), 55.f);
            float x0f = floorf(fx), y0f = floorf(fy);
            int x0 = (int)x0f, y0 = (int)y0f;
            float wx1 = fx - x0f, wy1 = fy - y0f;
            float wx0 = 1.f - wx1, wy0 = 1.f - wy1;
            bool hix = x0 >= W_ - 1;
            int   xb  = hix ? W_ - 2 : x0;
            float wxl = hix ? 0.f : wx0;
            float wxr = hix ? wx0 : wx1;
            int y0c = min(y0, H_ - 1);
            int y1c = min(y0 + 1, H_ - 1);
            float w00 = wy0 * wxl, w01 = wy0 * wxr, w10 = wy1 * wxl, w11 = wy1 * wxr;
            int ia0 = y0c * W_ + xb, ia1 = y1c * W_ + xb;
            f32x4 q00 = *(const f32x4*)(Lg + (pswz(ia0)     << 2));
            f32x4 q01 = *(const f32x4*)(Lg + (pswz(ia0 + 1) << 2));
            f32x4 q10 = *(const f32x4*)(Lg + (pswz(ia1)     << 2));
            f32x4 q11 = *(const f32x4*)(Lg + (pswz(ia1 + 1) << 2));
            out1[ob0 + n]        = w00*q00[0] + w01*q01[0] + w10*q10[0] + w11*q11[0];
            out1[ob0 + N_ + n]   = w00*q00[1] + w01*q01[1] + w10*q10[1] + w11*q11[1];
            out1[ob0 + 2*N_ + n] = w00*q00[2] + w01*q01[2] + w10*q10[2] + w11*q11[2];
            out1[ob0 + 3*N_ + n] = w00*q00[3] + w01*q01[3] + w10*q10[3] + w11*q11[3];
        }
    }
}

__device__ __forceinline__ bf16x8 afrag_f32(const float* __restrict__ wp, int ldk,
                                            int rowbase, int k0, int lane, int nrows) {
    int i = rowbase + (lane & 15);
    int k = k0 + ((lane >> 4) << 3);
    ushort8 u;
    if (i < nrows) {
        const float* s = wp + (size_t)i * ldk + k;
#pragma unroll
        for (int j = 0; j < 8; j++) u[j] = f2bf(s[j]);
    } else {
#pragma unroll
        for (int j = 0; j < 8; j++) u[j] = 0;
    }
    return __builtin_bit_cast(bf16x8, u);
}

template <bool BF16W>
__global__ __launch_bounds__(256) void mlp_kernel(
    const float* __restrict__ pf,
    const float* __restrict__ w0, const float* __restrict__ b0_,
    const float* __restrict__ w1, const float* __restrict__ b1,
    const float* __restrict__ w2, const float* __restrict__ b2,
    const unsigned short* __restrict__ wb,
    float* __restrict__ out0) {
    __shared__ unsigned int Xs[64 * 128];
    __shared__ unsigned int Y0s[64 * 64];
    const int t    = threadIdx.x;
    const int lane = t & 63;
    const int wave = t >> 6;
    const int bid  = blockIdx.x;
    const int b    = bid / NTILE;
    const int tile = bid - b * NTILE;
    const int n0   = tile * 64;
    const int nn_g = min(n0 + lane, N_ - 1);
    const int swz  = (lane & 7) << 2;
    const float* pfb = pf + (size_t)b * C_ * N_;
#pragma unroll
    for (int g8 = 0; g8 < 8; g8++) {
        int c0 = wave * 64 + g8 * 8;
        float v[8];
#pragma unroll
        for (int j = 0; j < 8; j++) v[j] = pfb[(size_t)(c0 + j) * N_ + nn_g];
        uint4v pk;
        pk[0] = pack2(v[0], v[1]); pk[1] = pack2(v[2], v[3]);
        pk[2] = pack2(v[4], v[5]); pk[3] = pack2(v[6], v[7]);
        *(uint4v*)(Xs + lane * 128 + ((c0 >> 1) ^ swz)) = pk;
    }
    bf16x8 a1[2][8];
#pragma unroll
    for (int mt = 0; mt < 2; mt++)
#pragma unroll
        for (int ks = 0; ks < 8; ks++)
            a1[mt][ks] = BF16W ? afrag_bf(wb, 256, (wave * 2 + mt) * 16, ks * 32, lane, 1 << 30)
                               : afrag_f32(w0, 256, (wave * 2 + mt) * 16, ks * 32, lane, 1 << 30);
    __syncthreads();
    const int cl = lane & 15;
    const int rh = lane >> 4;
    const int kq = rh << 3;
    f32x4 acc1[2][4] = {};
#pragma unroll
    for (int ks = 0; ks < 8; ks++) {
        bf16x8 bx[4];
#pragma unroll
        for (int nt = 0; nt < 4; nt++)
            bx[nt] = bfrag(Xs, 128, nt * 16 + cl, ks * 32 + kq);
#pragma unroll
        for (int mt = 0; mt < 2; mt++)
#pragma unroll
            for (int nt = 0; nt < 4; nt++)
                acc1[mt][nt] = __builtin_amdgcn_mfma_f32_16x16x32_bf16(
                    a1[mt][ks], bx[nt], acc1[mt][nt], 0, 0, 0);
    }
#pragma unroll
    for (int mt = 0; mt < 2; mt++) {
        int m0 = (wave * 2 + mt) * 16 + (rh << 2);
        f32x4 bias = *(const f32x4*)(b0_ + m0);
#pragma unroll
        for (int nt = 0; nt < 4; nt++) {
            int nn = nt * 16 + cl;
            float v0 = leaky(acc1[mt][nt][0] + bias[0]);
            float v1 = leaky(acc1[mt][nt][1] + bias[1]);
            float v2 = leaky(acc1[mt][nt][2] + bias[2]);
            float v3 = leaky(acc1[mt][nt][3] + bias[3]);
            int md = (m0 >> 1) ^ ((nn & 7) << 2);
            uint2v pk; pk[0] = pack2(v0, v1); pk[1] = pack2(v2, v3);
            *(uint2v*)(Y0s + nn * 64 + md) = pk;
        }
    }
    bf16x8 a2[12];
#pragma unroll
    for (int ks = 0; ks < 12; ks++)
        a2[ks] = BF16W ? afrag_bf(wb + WB1_OFF, 384, wave * 16, ks * 32, lane, 1 << 30)
                       : afrag_f32(w1, 384, wave * 16, ks * 32, lane, 1 << 30);
    __syncthreads();
    f32x4 acc2[4] = {};
#pragma unroll
    for (int ks = 0; ks < 12; ks++) {
#pragma unroll
        for (int nt = 0; nt < 4; nt++) {
            bf16x8 bx = (ks < 4) ? bfrag(Y0s, 64, nt * 16 + cl, ks * 32 + kq)
                                 : bfrag(Xs, 128, nt * 16 + cl, (ks - 4) * 32 + kq);
            acc2[nt] = __builtin_amdgcn_mfma_f32_16x16x32_bf16(a2[ks], bx, acc2[nt], 0, 0, 0);
        }
    }
    bf16x8 a3[10];
#pragma unroll
    for (int ks = 0; ks < 10; ks++)
        a3[ks] = BF16W ? afrag_bf(wb + WB2_OFF, 320, 0, ks * 32, lane, 5)
                       : afrag_f32(w2, 320, 0, ks * 32, lane, 5);
    __syncthreads();
    {
        int m0 = wave * 16 + (rh << 2);
        f32x4 bias = *(const f32x4*)(b1 + m0);
#pragma unroll
        for (int nt = 0; nt < 4; nt++) {
            int nn = nt * 16 + cl;
            float v0 = leaky(acc2[nt][0] + bias[0]);
            float v1 = leaky(acc2[nt][1] + bias[1]);
            float v2 = leaky(acc2[nt][2] + bias[2]);
            float v3 = leaky(acc2[nt][3] + bias[3]);
            int md = (m0 >> 1) ^ ((nn & 7) << 2);
            uint2v pk; pk[0] = pack2(v0, v1); pk[1] = pack2(v2, v3);
            *(uint2v*)(Y0s + nn * 32 + md) = pk;
        }
    }
    __syncthreads();
    {
        int nn = wave * 16 + cl;
        f32x4 acc3 = {};
#pragma unroll
        for (int ks = 0; ks < 10; ks++) {
            bf16x8 bx = (ks < 2) ? bfrag(Y0s, 32, nn, ks * 32 + kq)
                                 : bfrag(Xs, 128, nn, (ks - 2) * 32 + kq);
            acc3 = __builtin_amdgcn_mfma_f32_16x16x32_bf16(a3[ks], bx, acc3, 0, 0, 0);
        }
        int gn2 = n0 + nn;
        if (gn2 < N_) {
#pragma unroll
            for (int r2 = 0; r2 < 4; r2++) {
                int m = (rh << 2) + r2;
                if (m < 5) {
                    float v = acc3[r2] + b2[m];
                    v = v > 0.f ? v : 0.f;
                    out0[((size_t)b * 5 + m) * N_ + gn2] = v;
                }
            }
        }
    }
}

extern "C" void kernel_launch(void* const* d_in, const int* in_sizes, int n_in,
                              void* d_out, int out_size, void* d_ws, size_t ws_size,
                              hipStream_t stream) {
    const float* points = (const float*)d_in[0];
    const float* im     = (const float*)d_in[1];
    const float* w0     = (const float*)d_in[2];
    const float* b0     = (const float*)d_in[3];
    const float* w1     = (const float*)d_in[4];
    const float* b1     = (const float*)d_in[5];
    const float* w2     = (const float*)d_in[6];
    const float* b2     = (const float*)d_in[7];
    float* out0 = (float*)d_out;                   // mesh_align_feat [64][5*6890]
    float* out1 = out0 + (size_t)B_ * 5 * N_;      // point_feat      [64][256][6890]

    const size_t TBYTES = (size_t)B_ * HW_ * C_ * 4;   // imT fp32, 205.5 MB
    const size_t WBYTES = (size_t)WTOT * 2;
    const bool fok = (d_ws != nullptr) && (ws_size >= TBYTES + WBYTES);
    const bool wok = fok || ((d_ws != nullptr) && (ws_size >= WBYTES));
    float*          imT = (float*)d_ws;
    unsigned short* wb  = fok ? (unsigned short*)((char*)d_ws + TBYTES)
                              : (unsigned short*)d_ws;

    if (wok) {
        hipLaunchKernelGGL(wconv_kernel, dim3((WTOT + 255) / 256), dim3(256), 0, stream,
                           w0, w1, w2, wb);
    }
    if (fok) {
        hipLaunchKernelGGL(transpose_kernel, dim3(B_ * 196), dim3(256), 0, stream, im, imT);
        hipLaunchKernelGGL(fused_kernel, dim3(B_ * NTILE), dim3(256), 0, stream,
                           points, imT, b0, b1, b2, wb, out0, out1);
    } else {
        hipLaunchKernelGGL(gather_kernel, dim3(B_ * 64), dim3(512), 0, stream,
                           points, im, out1);
        if (wok) {
            hipLaunchKernelGGL(mlp_kernel<true>, dim3(B_ * NTILE), dim3(256), 0, stream,
                               out1, w0, b0, w1, b1, w2, b2, wb, out0);
        } else {
            hipLaunchKernelGGL(mlp_kernel<false>, dim3(B_ * NTILE), dim3(256), 0, stream,
                               out1, w0, b0, w1, b1, w2, b2,
                               (const unsigned short*)nullptr, out0);
        }
    }
}

// Round 7
// 382.471 us; speedup vs baseline: 1.0276x; 1.0276x over previous
//
#include <hip/hip_runtime.h>

#define B_    64
#define C_    256
#define H_    56
#define W_    56
#define N_    6890
#define HW_   3136
#define NTILE 108          // ceil(6890/64) MLP point tiles

#define WB1_OFF (128*256)
#define WB2_OFF (128*256 + 64*384)
#define WTOT    (128*256 + 64*384 + 5*320)   // 58944 bf16 weight elements

typedef __attribute__((ext_vector_type(8))) __bf16 bf16x8;
typedef __attribute__((ext_vector_type(8))) unsigned short ushort8;
typedef __attribute__((ext_vector_type(4))) float f32x4;
typedef __attribute__((ext_vector_type(2))) float f32x2;
typedef __attribute__((ext_vector_type(4))) unsigned int uint4v;
typedef __attribute__((ext_vector_type(2))) unsigned int uint2v;

__device__ __forceinline__ unsigned short f2bf(float f) {
    unsigned int u = __builtin_bit_cast(unsigned int, f);
    u += 0x7FFFu + ((u >> 16) & 1u);   // RTNE
    return (unsigned short)(u >> 16);
}
__device__ __forceinline__ unsigned int pack2(float lo, float hi) {
    return (unsigned int)f2bf(lo) | ((unsigned int)f2bf(hi) << 16);
}
__device__ __forceinline__ float bflo(unsigned int u) {
    return __builtin_bit_cast(float, u << 16);
}
__device__ __forceinline__ float bfhi(unsigned int u) {
    return __builtin_bit_cast(float, u & 0xffff0000u);
}
__device__ __forceinline__ float leaky(float v) { return v > 0.f ? v : 0.01f * v; }
__device__ __forceinline__ int pswz(int p) { return p ^ ((p >> 3) & 7); }

// ============================ kernel 0: weight bf16 pack ============================
__global__ void wconv_kernel(const float* __restrict__ w0, const float* __restrict__ w1,
                             const float* __restrict__ w2, unsigned short* __restrict__ wb) {
    int i = blockIdx.x * 256 + threadIdx.x;
    if (i >= WTOT) return;
    float v = (i < WB1_OFF) ? w0[i] : (i < WB2_OFF) ? w1[i - WB1_OFF] : w2[i - WB2_OFF];
    wb[i] = f2bf(v);
}

// ===================== kernel 1: bilinear gather -> bf16 x2 =========================
// One block per (batch, 4-channel chunk). Stage 4 planes (50 KB) to LDS once
// (image read from HBM exactly once, coalesced); LDS [pixel(swizzled)][4ch] ->
// each bilinear corner is one ds_read_b128. Output: x2 [b][64 chunk][n][2dw] bf16.
__global__ __launch_bounds__(512, 6) void gather_c(
    const float* __restrict__ points, const float* __restrict__ im,
    unsigned int* __restrict__ x2) {
    __shared__ float Ls[HW_ * 4];   // 50176 B

    const int t   = threadIdx.x;
    const int bid = blockIdx.x;
    const int b  = ((bid & 7) << 3) | ((bid >> 3) & 7);   // batch pinned to XCD bid&7
    const int ch = bid >> 6;                              // 0..63 chunk

    // ---- stage 4 planes, transposing to [pixel][4ch] with pixel swizzle ----
    const f32x4* im4 = (const f32x4*)(im + ((size_t)b * C_ + ch * 4) * HW_);
#pragma unroll
    for (int g0 = 0; g0 < 2; g0++) {
        int g = t + (g0 << 9);
        if (g < 784) {
            f32x4 r0 = im4[g], r1 = im4[784 + g], r2 = im4[1568 + g], r3 = im4[2352 + g];
#pragma unroll
            for (int i = 0; i < 4; i++) {
                f32x4 v; v[0] = r0[i]; v[1] = r1[i]; v[2] = r2[i]; v[3] = r3[i];
                *(f32x4*)(Ls + (pswz((g << 2) + i) << 2)) = v;
            }
        }
    }
    __syncthreads();

    // ---- gather all points for these 4 channels; emit bf16 uint2 ----
    const float* ptb = points + (size_t)b * N_ * 2;
    unsigned int* xout = x2 + ((size_t)((b << 6) + ch) * N_) * 2;
#pragma unroll 2
    for (int p = 0; p < 14; p++) {            // 14*512 >= 6890
        int n = t + (p << 9);
        if (n < N_) {
            f32x2 pt = *(const f32x2*)(ptb + 2 * n);
            float fx = fminf(fmaxf((pt.x + 1.f) * 27.5f, 0.f), 55.f);
            float fy = fminf(fmaxf((pt.y + 1.f) * 27.5f, 0.f), 55.f);
            float x0f = floorf(fx), y0f = floorf(fy);
            int x0 = (int)x0f, y0 = (int)y0f;
            float wx1 = fx - x0f, wy1 = fy - y0f;
            float wx0 = 1.f - wx1, wy0 = 1.f - wy1;
            bool hix = x0 >= W_ - 1;          // fx==55 edge: weight moves to right tap
            int   xb  = hix ? W_ - 2 : x0;
            float wxl = hix ? 0.f : wx0;
            float wxr = hix ? wx0 : wx1;
            int y0c = min(y0, H_ - 1);
            int y1c = min(y0 + 1, H_ - 1);    // fy==55 edge: wy1==0
            float w00 = wy0 * wxl, w01 = wy0 * wxr;
            float w10 = wy1 * wxl, w11 = wy1 * wxr;
            int ia0 = y0c * W_ + xb, ia1 = y1c * W_ + xb;

            f32x4 q00 = *(const f32x4*)(Ls + (pswz(ia0)     << 2));
            f32x4 q01 = *(const f32x4*)(Ls + (pswz(ia0 + 1) << 2));
            f32x4 q10 = *(const f32x4*)(Ls + (pswz(ia1)     << 2));
            f32x4 q11 = *(const f32x4*)(Ls + (pswz(ia1 + 1) << 2));
            float v0 = w00*q00[0] + w01*q01[0] + w10*q10[0] + w11*q11[0];
            float v1 = w00*q00[1] + w01*q01[1] + w10*q10[1] + w11*q11[1];
            float v2 = w00*q00[2] + w01*q01[2] + w10*q10[2] + w11*q11[2];
            float v3 = w00*q00[3] + w01*q01[3] + w10*q10[3] + w11*q11[3];
            uint2v pk; pk[0] = pack2(v0, v1); pk[1] = pack2(v2, v3);
            *(uint2v*)(xout + (size_t)n * 2) = pk;   // coalesced 8B over consecutive n
        }
    }
}

// ================= kernel 2: MFMA MLP (x2 in, pf fp32 + mesh out) ===================
__device__ __forceinline__ bf16x8 afrag_bf(const unsigned short* __restrict__ wb, int ldk,
                                           int rowbase, int k0, int lane, int nrows) {
    int i = rowbase + (lane & 15);
    int k = k0 + ((lane >> 4) << 3);
    if (i < nrows) return __builtin_bit_cast(bf16x8, *(const ushort8*)(wb + (size_t)i * ldk + k));
    ushort8 z = {0, 0, 0, 0, 0, 0, 0, 0};
    return __builtin_bit_cast(bf16x8, z);
}
// B-fragment from swizzled LDS: buf[n][cd ^ ((n&7)<<2)], 4 dwords at k0
__device__ __forceinline__ bf16x8 bfrag(const unsigned int* buf, int rowstride_dw,
                                        int n, int k0) {
    int cd = (k0 >> 1) ^ ((n & 7) << 2);
    uint4v v = *(const uint4v*)(buf + n * rowstride_dw + cd);
    return __builtin_bit_cast(bf16x8, v);
}

__global__ __launch_bounds__(256) void mlp_c(
    const unsigned int* __restrict__ x2,
    const float* __restrict__ b0_, const float* __restrict__ b1,
    const float* __restrict__ b2, const unsigned short* __restrict__ wb,
    float* __restrict__ out0, float* __restrict__ out1) {
    __shared__ unsigned int Xs[64 * 128];   // X  [n=64][c=256] bf16, swizzled (32KB)
    __shared__ unsigned int Y0s[64 * 64];   // Y0 [n][m=128] bf16 (16KB); Y1 aliased in

    const int t    = threadIdx.x;
    const int lane = t & 63;
    const int wave = t >> 6;
    const int bid  = blockIdx.x;
    const int b    = bid / NTILE;
    const int tile = bid - b * NTILE;
    const int n0   = tile * 64;

    const int  nn_g = min(n0 + lane, N_ - 1);
    const bool okn  = (n0 + lane) < N_;
    const int  swz  = (lane & 7) << 2;

    // ---- stage X from x2 (16 b64 loads) + expand pf fp32 in the same pass ----
    float* pfb = out1 + (size_t)b * C_ * N_ + n0;
#pragma unroll
    for (int j = 0; j < 8; j++) {
        int d2a = wave * 16 + 2 * j;                         // chunk pair base
        const unsigned int* src = x2 + ((size_t)((b << 6) + d2a) * N_ + nn_g) * 2;
        uint2v q0 = *(const uint2v*)src;                     // chunk d2a   (ch 4d2a..+3)
        uint2v q1 = *(const uint2v*)(src + 2 * (size_t)N_);  // chunk d2a+1 (ch 4d2a+4..+7)
        if (okn) {                                           // pf fp32 (bf16-expanded)
            int c0 = 4 * d2a;
            pfb[(size_t)(c0    ) * N_ + lane] = bflo(q0[0]);
            pfb[(size_t)(c0 + 1) * N_ + lane] = bfhi(q0[0]);
            pfb[(size_t)(c0 + 2) * N_ + lane] = bflo(q0[1]);
            pfb[(size_t)(c0 + 3) * N_ + lane] = bfhi(q0[1]);
            pfb[(size_t)(c0 + 4) * N_ + lane] = bflo(q1[0]);
            pfb[(size_t)(c0 + 5) * N_ + lane] = bfhi(q1[0]);
            pfb[(size_t)(c0 + 6) * N_ + lane] = bflo(q1[1]);
            pfb[(size_t)(c0 + 7) * N_ + lane] = bfhi(q1[1]);
        }
        uint4v pk; pk[0] = q0[0]; pk[1] = q0[1]; pk[2] = q1[0]; pk[3] = q1[1];
        *(uint4v*)(Xs + lane * 128 + ((wave * 32 + 4 * j) ^ swz)) = pk;
    }

    // ---- layer 1 A preload ----
    bf16x8 a1[2][8];
#pragma unroll
    for (int mt = 0; mt < 2; mt++)
#pragma unroll
        for (int ks = 0; ks < 8; ks++)
            a1[mt][ks] = afrag_bf(wb, 256, (wave * 2 + mt) * 16, ks * 32, lane, 1 << 30);

    __syncthreads();

    const int cl = lane & 15;
    const int rh = lane >> 4;
    const int kq = rh << 3;

    // ---- layer 1: Y0[128,64] = leaky(W0 @ X + b0) ----
    f32x4 acc1[2][4] = {};
#pragma unroll
    for (int ks = 0; ks < 8; ks++) {
        bf16x8 bx[4];
#pragma unroll
        for (int nt = 0; nt < 4; nt++)
            bx[nt] = bfrag(Xs, 128, nt * 16 + cl, ks * 32 + kq);
#pragma unroll
        for (int mt = 0; mt < 2; mt++)
#pragma unroll
            for (int nt = 0; nt < 4; nt++)
                acc1[mt][nt] = __builtin_amdgcn_mfma_f32_16x16x32_bf16(
                    a1[mt][ks], bx[nt], acc1[mt][nt], 0, 0, 0);
    }

#pragma unroll
    for (int mt = 0; mt < 2; mt++) {
        int m0 = (wave * 2 + mt) * 16 + (rh << 2);
        f32x4 bias = *(const f32x4*)(b0_ + m0);
#pragma unroll
        for (int nt = 0; nt < 4; nt++) {
            int nn = nt * 16 + cl;
            float v0 = leaky(acc1[mt][nt][0] + bias[0]);
            float v1 = leaky(acc1[mt][nt][1] + bias[1]);
            float v2 = leaky(acc1[mt][nt][2] + bias[2]);
            float v3 = leaky(acc1[mt][nt][3] + bias[3]);
            int md = (m0 >> 1) ^ ((nn & 7) << 2);
            uint2v pk; pk[0] = pack2(v0, v1); pk[1] = pack2(v2, v3);
            *(uint2v*)(Y0s + nn * 64 + md) = pk;
        }
    }

    // ---- layer 2 A preload: K = 384 = [Y0(128) | X(256)] ----
    bf16x8 a2[12];
#pragma unroll
    for (int ks = 0; ks < 12; ks++)
        a2[ks] = afrag_bf(wb + WB1_OFF, 384, wave * 16, ks * 32, lane, 1 << 30);

    __syncthreads();

    f32x4 acc2[4] = {};
#pragma unroll
    for (int ks = 0; ks < 12; ks++) {
#pragma unroll
        for (int nt = 0; nt < 4; nt++) {
            bf16x8 bx = (ks < 4) ? bfrag(Y0s, 64, nt * 16 + cl, ks * 32 + kq)
                                 : bfrag(Xs, 128, nt * 16 + cl, (ks - 4) * 32 + kq);
            acc2[nt] = __builtin_amdgcn_mfma_f32_16x16x32_bf16(a2[ks], bx, acc2[nt], 0, 0, 0);
        }
    }

    // layer 3 A preload (W2 zero-padded to 16 rows); K = 320 = [Y1(64) | X(256)]
    bf16x8 a3[10];
#pragma unroll
    for (int ks = 0; ks < 10; ks++)
        a3[ks] = afrag_bf(wb + WB2_OFF, 320, 0, ks * 32, lane, 5);

    __syncthreads();   // all waves done READING Y0s before Y1 overwrites it

    // ---- epilogue 2 -> Y1 (aliases Y0s) ----
    {
        int m0 = wave * 16 + (rh << 2);
        f32x4 bias = *(const f32x4*)(b1 + m0);
#pragma unroll
        for (int nt = 0; nt < 4; nt++) {
            int nn = nt * 16 + cl;
            float v0 = leaky(acc2[nt][0] + bias[0]);
            float v1 = leaky(acc2[nt][1] + bias[1]);
            float v2 = leaky(acc2[nt][2] + bias[2]);
            float v3 = leaky(acc2[nt][3] + bias[3]);
            int md = (m0 >> 1) ^ ((nn & 7) << 2);
            uint2v pk; pk[0] = pack2(v0, v1); pk[1] = pack2(v2, v3);
            *(uint2v*)(Y0s + nn * 32 + md) = pk;   // Y1 layout: [n][32 dwords]
        }
    }

    __syncthreads();

    // ---- layer 3: each wave owns one 16-col N-tile ----
    {
        int nn = wave * 16 + cl;
        f32x4 acc3 = {};
#pragma unroll
        for (int ks = 0; ks < 10; ks++) {
            bf16x8 bx = (ks < 2) ? bfrag(Y0s, 32, nn, ks * 32 + kq)
                                 : bfrag(Xs, 128, nn, (ks - 2) * 32 + kq);
            acc3 = __builtin_amdgcn_mfma_f32_16x16x32_bf16(a3[ks], bx, acc3, 0, 0, 0);
        }
        int gn2 = n0 + nn;
        if (gn2 < N_) {
#pragma unroll
            for (int r2 = 0; r2 < 4; r2++) {
                int m = (rh << 2) + r2;
                if (m < 5) {
                    float v = acc3[r2] + b2[m];
                    v = v > 0.f ? v : 0.f;   // final relu
                    out0[((size_t)b * 5 + m) * N_ + gn2] = v;
                }
            }
        }
    }
}

// ===================== fallback path (round-4): gather + mlp ========================
__global__ __launch_bounds__(512, 6) void gather_kernel(
    const float* __restrict__ points, const float* __restrict__ im,
    float* __restrict__ out1) {
    __shared__ float Lg[HW_ * 4];
    const int t   = threadIdx.x;
    const int bid = blockIdx.x;
    const int b  = ((bid & 7) << 3) | ((bid >> 3) & 7);
    const int ch = bid >> 6;
    const f32x4* im4 = (const f32x4*)(im + ((size_t)b * C_ + ch * 4) * HW_);
#pragma unroll
    for (int g0 = 0; g0 < 2; g0++) {
        int g = t + (g0 << 9);
        if (g < 784) {
            f32x4 r0 = im4[g], r1 = im4[784 + g], r2 = im4[1568 + g], r3 = im4[2352 + g];
#pragma unroll
            for (int i = 0; i < 4; i++) {
                f32x4 v; v[0] = r0[i]; v[1] = r1[i]; v[2] = r2[i]; v[3] = r3[i];
                *(f32x4*)(Lg + (pswz((g << 2) + i) << 2)) = v;
            }
        }
    }
    __syncthreads();
    const float* ptb = points + (size_t)b * N_ * 2;
    const size_t ob0 = ((size_t)b * C_ + ch * 4) * N_;
#pragma unroll 2
    for (int p = 0; p < 14; p++) {
        int n = t + (p << 9);
        if (n < N_) {
            f32x2 pt = *(const f32x2*)(ptb + 2 * n);
            float fx = fminf(fmaxf((pt.x + 1.f) * 27.5f, 0.f), 55.f);
            float fy = fminf(fmaxf((pt.y + 1.f) * 27.5f, 0.f), 55.f);
            float x0f = floorf(fx), y0f = floorf(fy);
            int x0 = (int)x0f, y0 = (int)y0f;
            float wx1 = fx - x0f, wy1 = fy - y0f;
            float wx0 = 1.f - wx1, wy0 = 1.f - wy1;
            bool hix = x0 >= W_ - 1;
            int   xb  = hix ? W_ - 2 : x0;
            float wxl = hix ? 0.f : wx0;
            float wxr = hix ? wx0 : wx1;
            int y0c = min(y0, H_ - 1);
            int y1c = min(y0 + 1, H_ - 1);
            float w00 = wy0 * wxl, w01 = wy0 * wxr, w10 = wy1 * wxl, w11 = wy1 * wxr;
            int ia0 = y0c * W_ + xb, ia1 = y1c * W_ + xb;
            f32x4 q00 = *(const f32x4*)(Lg + (pswz(ia0)     << 2));
            f32x4 q01 = *(const f32x4*)(Lg + (pswz(ia0 + 1) << 2));
            f32x4 q10 = *(const f32x4*)(Lg + (pswz(ia1)     << 2));
            f32x4 q11 = *(const f32x4*)(Lg + (pswz(ia1 + 1) << 2));
            out1[ob0 + n]        = w00*q00[0] + w01*q01[0] + w10*q10[0] + w11*q11[0];
            out1[ob0 + N_ + n]   = w00*q00[1] + w01*q01[1] + w10*q10[1] + w11*q11[1];
            out1[ob0 + 2*N_ + n] = w00*q00[2] + w01*q01[2] + w10*q10[2] + w11*q11[2];
            out1[ob0 + 3*N_ + n] = w00*q00[3] + w01*q01[3] + w10*q10[3] + w11*q11[3];
        }
    }
}

__device__ __forceinline__ bf16x8 afrag_f32(const float* __restrict__ wp, int ldk,
                                            int rowbase, int k0, int lane, int nrows) {
    int i = rowbase + (lane & 15);
    int k = k0 + ((lane >> 4) << 3);
    ushort8 u;
    if (i < nrows) {
        const float* s = wp + (size_t)i * ldk + k;
#pragma unroll
        for (int j = 0; j < 8; j++) u[j] = f2bf(s[j]);
    } else {
#pragma unroll
        for (int j = 0; j < 8; j++) u[j] = 0;
    }
    return __builtin_bit_cast(bf16x8, u);
}

__global__ __launch_bounds__(256) void mlp_fallback(
    const float* __restrict__ pf,
    const float* __restrict__ w0, const float* __restrict__ b0_,
    const float* __restrict__ w1, const float* __restrict__ b1,
    const float* __restrict__ w2, const float* __restrict__ b2,
    float* __restrict__ out0) {
    __shared__ unsigned int Xs[64 * 128];
    __shared__ unsigned int Y0s[64 * 64];
    const int t    = threadIdx.x;
    const int lane = t & 63;
    const int wave = t >> 6;
    const int bid  = blockIdx.x;
    const int b    = bid / NTILE;
    const int tile = bid - b * NTILE;
    const int n0   = tile * 64;
    const int nn_g = min(n0 + lane, N_ - 1);
    const int swz  = (lane & 7) << 2;
    const float* pfb = pf + (size_t)b * C_ * N_;
#pragma unroll
    for (int g8 = 0; g8 < 8; g8++) {
        int c0 = wave * 64 + g8 * 8;
        float v[8];
#pragma unroll
        for (int j = 0; j < 8; j++) v[j] = pfb[(size_t)(c0 + j) * N_ + nn_g];
        uint4v pk;
        pk[0] = pack2(v[0], v[1]); pk[1] = pack2(v[2], v[3]);
        pk[2] = pack2(v[4], v[5]); pk[3] = pack2(v[6], v[7]);
        *(uint4v*)(Xs + lane * 128 + ((c0 >> 1) ^ swz)) = pk;
    }
    bf16x8 a1[2][8];
#pragma unroll
    for (int mt = 0; mt < 2; mt++)
#pragma unroll
        for (int ks = 0; ks < 8; ks++)
            a1[mt][ks] = afrag_f32(w0, 256, (wave * 2 + mt) * 16, ks * 32, lane, 1 << 30);
    __syncthreads();
    const int cl = lane & 15;
    const int rh = lane >> 4;
    const int kq = rh << 3;
    f32x4 acc1[2][4] = {};
#pragma unroll
    for (int ks = 0; ks < 8; ks++) {
        bf16x8 bx[4];
#pragma unroll
        for (int nt = 0; nt < 4; nt++)
            bx[nt] = bfrag(Xs, 128, nt * 16 + cl, ks * 32 + kq);
#pragma unroll
        for (int mt = 0; mt < 2; mt++)
#pragma unroll
            for (int nt = 0; nt < 4; nt++)
                acc1[mt][nt] = __builtin_amdgcn_mfma_f32_16x16x32_bf16(
                    a1[mt][ks], bx[nt], acc1[mt][nt], 0, 0, 0);
    }
#pragma unroll
    for (int mt = 0; mt < 2; mt++) {
        int m0 = (wave * 2 + mt) * 16 + (rh << 2);
        f32x4 bias = *(const f32x4*)(b0_ + m0);
#pragma unroll
        for (int nt = 0; nt < 4; nt++) {
            int nn = nt * 16 + cl;
            float v0 = leaky(acc1[mt][nt][0] + bias[0]);
            float v1 = leaky(acc1[mt][nt][1] + bias[1]);
            float v2 = leaky(acc1[mt][nt][2] + bias[2]);
            float v3 = leaky(acc1[mt][nt][3] + bias[3]);
            int md = (m0 >> 1) ^ ((nn & 7) << 2);
            uint2v pk; pk[0] = pack2(v0, v1); pk[1] = pack2(v2, v3);
            *(uint2v*)(Y0s + nn * 64 + md) = pk;
        }
    }
    bf16x8 a2[12];
#pragma unroll
    for (int ks = 0; ks < 12; ks++)
        a2[ks] = afrag_f32(w1, 384, wave * 16, ks * 32, lane, 1 << 30);
    __syncthreads();
    f32x4 acc2[4] = {};
#pragma unroll
    for (int ks = 0; ks < 12; ks++) {
#pragma unroll
        for (int nt = 0; nt < 4; nt++) {
            bf16x8 bx = (ks < 4) ? bfrag(Y0s, 64, nt * 16 + cl, ks * 32 + kq)
                                 : bfrag(Xs, 128, nt * 16 + cl, (ks - 4) * 32 + kq);
            acc2[nt] = __builtin_amdgcn_mfma_f32_16x16x32_bf16(a2[ks], bx, acc2[nt], 0, 0, 0);
        }
    }
    bf16x8 a3[10];
#pragma unroll
    for (int ks = 0; ks < 10; ks++)
        a3[ks] = afrag_f32(w2, 320, 0, ks * 32, lane, 5);
    __syncthreads();
    {
        int m0 = wave * 16 + (rh << 2);
        f32x4 bias = *(const f32x4*)(b1 + m0);
#pragma unroll
        for (int nt = 0; nt < 4; nt++) {
            int nn = nt * 16 + cl;
            float v0 = leaky(acc2[nt][0] + bias[0]);
            float v1 = leaky(acc2[nt][1] + bias[1]);
            float v2 = leaky(acc2[nt][2] + bias[2]);
            float v3 = leaky(acc2[nt][3] + bias[3]);
            int md = (m0 >> 1) ^ ((nn & 7) << 2);
            uint2v pk; pk[0] = pack2(v0, v1); pk[1] = pack2(v2, v3);
            *(uint2v*)(Y0s + nn * 32 + md) = pk;
        }
    }
    __syncthreads();
    {
        int nn = wave * 16 + cl;
        f32x4 acc3 = {};
#pragma unroll
        for (int ks = 0; ks < 10; ks++) {
            bf16x8 bx = (ks < 2) ? bfrag(Y0s, 32, nn, ks * 32 + kq)
                                 : bfrag(Xs, 128, nn, (ks - 2) * 32 + kq);
            acc3 = __builtin_amdgcn_mfma_f32_16x16x32_bf16(a3[ks], bx, acc3, 0, 0, 0);
        }
        int gn2 = n0 + nn;
        if (gn2 < N_) {
#pragma unroll
            for (int r2 = 0; r2 < 4; r2++) {
                int m = (rh << 2) + r2;
                if (m < 5) {
                    float v = acc3[r2] + b2[m];
                    v = v > 0.f ? v : 0.f;
                    out0[((size_t)b * 5 + m) * N_ + gn2] = v;
                }
            }
        }
    }
}

extern "C" void kernel_launch(void* const* d_in, const int* in_sizes, int n_in,
                              void* d_out, int out_size, void* d_ws, size_t ws_size,
                              hipStream_t stream) {
    const float* points = (const float*)d_in[0];
    const float* im     = (const float*)d_in[1];
    const float* w0     = (const float*)d_in[2];
    const float* b0     = (const float*)d_in[3];
    const float* w1     = (const float*)d_in[4];
    const float* b1     = (const float*)d_in[5];
    const float* w2     = (const float*)d_in[6];
    const float* b2     = (const float*)d_in[7];
    float* out0 = (float*)d_out;                   // mesh_align_feat [64][5*6890]
    float* out1 = out0 + (size_t)B_ * 5 * N_;      // point_feat      [64][256][6890]

    const size_t XBYTES = (size_t)B_ * 64 * N_ * 8;   // x2 bf16: 64 chunks x uint2, 225.8 MB
    const size_t WBYTES = (size_t)WTOT * 2;
    const bool cok = (d_ws != nullptr) && (ws_size >= XBYTES + WBYTES);
    unsigned int*   x2 = (unsigned int*)d_ws;
    unsigned short* wb = (unsigned short*)((char*)d_ws + XBYTES);

    if (cok) {
        hipLaunchKernelGGL(wconv_kernel, dim3((WTOT + 255) / 256), dim3(256), 0, stream,
                           w0, w1, w2, wb);
        hipLaunchKernelGGL(gather_c, dim3(B_ * 64), dim3(512), 0, stream,
                           points, im, x2);
        hipLaunchKernelGGL(mlp_c, dim3(B_ * NTILE), dim3(256), 0, stream,
                           x2, b0, b1, b2, wb, out0, out1);
    } else {
        hipLaunchKernelGGL(gather_kernel, dim3(B_ * 64), dim3(512), 0, stream,
                           points, im, out1);
        hipLaunchKernelGGL(mlp_fallback, dim3(B_ * NTILE), dim3(256), 0, stream,
                           out1, w0, b0, w1, b1, w2, b2, out0);
    }
}

// Round 8
// 355.717 us; speedup vs baseline: 1.1049x; 1.0752x over previous
//
#include <hip/hip_runtime.h>

#define B_    64
#define C_    256
#define H_    56
#define W_    56
#define N_    6890
#define HW_   3136
#define NTILE 108          // ceil(6890/64) MLP point tiles

#define WB1_OFF (128*256)
#define WB2_OFF (128*256 + 64*384)
#define WTOT    (128*256 + 64*384 + 5*320)   // 58944 bf16 weight elements

typedef __attribute__((ext_vector_type(8))) __bf16 bf16x8;
typedef __attribute__((ext_vector_type(8))) unsigned short ushort8;
typedef __attribute__((ext_vector_type(4))) float f32x4;
typedef __attribute__((ext_vector_type(2))) float f32x2;
typedef __attribute__((ext_vector_type(4))) unsigned int uint4v;
typedef __attribute__((ext_vector_type(2))) unsigned int uint2v;

__device__ __forceinline__ unsigned short f2bf(float f) {
    unsigned int u = __builtin_bit_cast(unsigned int, f);
    u += 0x7FFFu + ((u >> 16) & 1u);   // RTNE
    return (unsigned short)(u >> 16);
}
__device__ __forceinline__ unsigned int pack2(float lo, float hi) {
    return (unsigned int)f2bf(lo) | ((unsigned int)f2bf(hi) << 16);
}
__device__ __forceinline__ float bflo(unsigned int u) {
    return __builtin_bit_cast(float, u << 16);
}
__device__ __forceinline__ float bfhi(unsigned int u) {
    return __builtin_bit_cast(float, u & 0xffff0000u);
}
__device__ __forceinline__ float leaky(float v) { return v > 0.f ? v : 0.01f * v; }
__device__ __forceinline__ int pswz(int p) { return p ^ ((p >> 3) & 7); }

// ============================ kernel 0: weight bf16 pack ============================
__global__ void wconv_kernel(const float* __restrict__ w0, const float* __restrict__ w1,
                             const float* __restrict__ w2, unsigned short* __restrict__ wb) {
    int i = blockIdx.x * 256 + threadIdx.x;
    if (i >= WTOT) return;
    float v = (i < WB1_OFF) ? w0[i] : (i < WB2_OFF) ? w1[i - WB1_OFF] : w2[i - WB2_OFF];
    wb[i] = f2bf(v);
}

// ===================== kernel 1: bilinear gather -> bf16 x2 =========================
// One block per (batch, 4-channel chunk). Stage 4 planes (50 KB) to LDS once
// (image read from HBM exactly once, coalesced); LDS [pixel(swizzled)][4ch] ->
// each bilinear corner is one ds_read_b128. Output: x2 [b][64 chunk][n][2dw] bf16.
__global__ __launch_bounds__(512, 6) void gather_c(
    const float* __restrict__ points, const float* __restrict__ im,
    unsigned int* __restrict__ x2) {
    __shared__ float Ls[HW_ * 4];   // 50176 B

    const int t   = threadIdx.x;
    const int bid = blockIdx.x;
    const int b  = ((bid & 7) << 3) | ((bid >> 3) & 7);   // batch pinned to XCD bid&7
    const int ch = bid >> 6;                              // 0..63 chunk

    // ---- stage 4 planes, transposing to [pixel][4ch] with pixel swizzle ----
    const f32x4* im4 = (const f32x4*)(im + ((size_t)b * C_ + ch * 4) * HW_);
#pragma unroll
    for (int g0 = 0; g0 < 2; g0++) {
        int g = t + (g0 << 9);
        if (g < 784) {
            f32x4 r0 = im4[g], r1 = im4[784 + g], r2 = im4[1568 + g], r3 = im4[2352 + g];
#pragma unroll
            for (int i = 0; i < 4; i++) {
                f32x4 v; v[0] = r0[i]; v[1] = r1[i]; v[2] = r2[i]; v[3] = r3[i];
                *(f32x4*)(Ls + (pswz((g << 2) + i) << 2)) = v;
            }
        }
    }
    __syncthreads();

    // ---- gather all points for these 4 channels; emit bf16 uint2 ----
    const float* ptb = points + (size_t)b * N_ * 2;
    unsigned int* xout = x2 + ((size_t)((b << 6) + ch) * N_) * 2;
#pragma unroll 2
    for (int p = 0; p < 14; p++) {            // 14*512 >= 6890
        int n = t + (p << 9);
        if (n < N_) {
            f32x2 pt = *(const f32x2*)(ptb + 2 * n);
            float fx = fminf(fmaxf((pt.x + 1.f) * 27.5f, 0.f), 55.f);
            float fy = fminf(fmaxf((pt.y + 1.f) * 27.5f, 0.f), 55.f);
            float x0f = floorf(fx), y0f = floorf(fy);
            int x0 = (int)x0f, y0 = (int)y0f;
            float wx1 = fx - x0f, wy1 = fy - y0f;
            float wx0 = 1.f - wx1, wy0 = 1.f - wy1;
            bool hix = x0 >= W_ - 1;          // fx==55 edge: weight moves to right tap
            int   xb  = hix ? W_ - 2 : x0;
            float wxl = hix ? 0.f : wx0;
            float wxr = hix ? wx0 : wx1;
            int y0c = min(y0, H_ - 1);
            int y1c = min(y0 + 1, H_ - 1);    // fy==55 edge: wy1==0
            float w00 = wy0 * wxl, w01 = wy0 * wxr;
            float w10 = wy1 * wxl, w11 = wy1 * wxr;
            int ia0 = y0c * W_ + xb, ia1 = y1c * W_ + xb;

            f32x4 q00 = *(const f32x4*)(Ls + (pswz(ia0)     << 2));
            f32x4 q01 = *(const f32x4*)(Ls + (pswz(ia0 + 1) << 2));
            f32x4 q10 = *(const f32x4*)(Ls + (pswz(ia1)     << 2));
            f32x4 q11 = *(const f32x4*)(Ls + (pswz(ia1 + 1) << 2));
            float v0 = w00*q00[0] + w01*q01[0] + w10*q10[0] + w11*q11[0];
            float v1 = w00*q00[1] + w01*q01[1] + w10*q10[1] + w11*q11[1];
            float v2 = w00*q00[2] + w01*q01[2] + w10*q10[2] + w11*q11[2];
            float v3 = w00*q00[3] + w01*q01[3] + w10*q10[3] + w11*q11[3];
            uint2v pk; pk[0] = pack2(v0, v1); pk[1] = pack2(v2, v3);
            *(uint2v*)(xout + (size_t)n * 2) = pk;   // coalesced 8B over consecutive n
        }
    }
}

// ================= kernel 2: MFMA MLP (x2 in, pf fp32 + mesh out) ===================
__device__ __forceinline__ bf16x8 afrag_bf(const unsigned short* __restrict__ wb, int ldk,
                                           int rowbase, int k0, int lane, int nrows) {
    int i = rowbase + (lane & 15);
    int k = k0 + ((lane >> 4) << 3);
    if (i < nrows) return __builtin_bit_cast(bf16x8, *(const ushort8*)(wb + (size_t)i * ldk + k));
    ushort8 z = {0, 0, 0, 0, 0, 0, 0, 0};
    return __builtin_bit_cast(bf16x8, z);
}
// B-fragment from swizzled LDS: buf[n][cd ^ ((n&7)<<2)], 4 dwords at k0
__device__ __forceinline__ bf16x8 bfrag(const unsigned int* buf, int rowstride_dw,
                                        int n, int k0) {
    int cd = (k0 >> 1) ^ ((n & 7) << 2);
    uint4v v = *(const uint4v*)(buf + n * rowstride_dw + cd);
    return __builtin_bit_cast(bf16x8, v);
}

__global__ __launch_bounds__(256) void mlp_c(
    const unsigned int* __restrict__ x2,
    const float* __restrict__ b0_, const float* __restrict__ b1,
    const float* __restrict__ b2, const unsigned short* __restrict__ wb,
    float* __restrict__ out0, float* __restrict__ out1) {
    __shared__ unsigned int Xs[64 * 128];   // X  [n=64][c=256] bf16, swizzled (32KB)
    __shared__ unsigned int Y0s[64 * 64];   // Y0 [n][m=128] bf16 (16KB); Y1 aliased in

    const int t    = threadIdx.x;
    const int lane = t & 63;
    const int wave = t >> 6;
    const int bid  = blockIdx.x;
    const int b    = bid / NTILE;
    const int tile = bid - b * NTILE;
    const int n0   = tile * 64;

    const int  nn_g = min(n0 + lane, N_ - 1);
    const bool okn  = (n0 + lane) < N_;
    const int  swz  = (lane & 7) << 2;

    // ---- stage X from x2 (16 b64 loads); KEEP the dwords in registers for the
    //      deferred pf expansion (no global stores before any barrier!) ----
    uint2v qa[8], qb[8];
#pragma unroll
    for (int j = 0; j < 8; j++) {
        int d2a = wave * 16 + 2 * j;                         // chunk pair base
        const unsigned int* src = x2 + ((size_t)((b << 6) + d2a) * N_ + nn_g) * 2;
        qa[j] = *(const uint2v*)src;                         // chunk d2a   (ch 4d2a..+3)
        qb[j] = *(const uint2v*)(src + 2 * (size_t)N_);      // chunk d2a+1 (ch +4..+7)
        uint4v pk; pk[0] = qa[j][0]; pk[1] = qa[j][1]; pk[2] = qb[j][0]; pk[3] = qb[j][1];
        *(uint4v*)(Xs + lane * 128 + ((wave * 32 + 4 * j) ^ swz)) = pk;
    }

    // ---- layer 1 A preload ----
    bf16x8 a1[2][8];
#pragma unroll
    for (int mt = 0; mt < 2; mt++)
#pragma unroll
        for (int ks = 0; ks < 8; ks++)
            a1[mt][ks] = afrag_bf(wb, 256, (wave * 2 + mt) * 16, ks * 32, lane, 1 << 30);

    __syncthreads();

    const int cl = lane & 15;
    const int rh = lane >> 4;
    const int kq = rh << 3;

    // ---- layer 1: Y0[128,64] = leaky(W0 @ X + b0) ----
    f32x4 acc1[2][4] = {};
#pragma unroll
    for (int ks = 0; ks < 8; ks++) {
        bf16x8 bx[4];
#pragma unroll
        for (int nt = 0; nt < 4; nt++)
            bx[nt] = bfrag(Xs, 128, nt * 16 + cl, ks * 32 + kq);
#pragma unroll
        for (int mt = 0; mt < 2; mt++)
#pragma unroll
            for (int nt = 0; nt < 4; nt++)
                acc1[mt][nt] = __builtin_amdgcn_mfma_f32_16x16x32_bf16(
                    a1[mt][ks], bx[nt], acc1[mt][nt], 0, 0, 0);
    }

#pragma unroll
    for (int mt = 0; mt < 2; mt++) {
        int m0 = (wave * 2 + mt) * 16 + (rh << 2);
        f32x4 bias = *(const f32x4*)(b0_ + m0);
#pragma unroll
        for (int nt = 0; nt < 4; nt++) {
            int nn = nt * 16 + cl;
            float v0 = leaky(acc1[mt][nt][0] + bias[0]);
            float v1 = leaky(acc1[mt][nt][1] + bias[1]);
            float v2 = leaky(acc1[mt][nt][2] + bias[2]);
            float v3 = leaky(acc1[mt][nt][3] + bias[3]);
            int md = (m0 >> 1) ^ ((nn & 7) << 2);
            uint2v pk; pk[0] = pack2(v0, v1); pk[1] = pack2(v2, v3);
            *(uint2v*)(Y0s + nn * 64 + md) = pk;
        }
    }

    // ---- layer 2 A preload: K = 384 = [Y0(128) | X(256)] ----
    bf16x8 a2[12];
#pragma unroll
    for (int ks = 0; ks < 12; ks++)
        a2[ks] = afrag_bf(wb + WB1_OFF, 384, wave * 16, ks * 32, lane, 1 << 30);

    __syncthreads();

    f32x4 acc2[4] = {};
#pragma unroll
    for (int ks = 0; ks < 12; ks++) {
#pragma unroll
        for (int nt = 0; nt < 4; nt++) {
            bf16x8 bx = (ks < 4) ? bfrag(Y0s, 64, nt * 16 + cl, ks * 32 + kq)
                                 : bfrag(Xs, 128, nt * 16 + cl, (ks - 4) * 32 + kq);
            acc2[nt] = __builtin_amdgcn_mfma_f32_16x16x32_bf16(a2[ks], bx, acc2[nt], 0, 0, 0);
        }
    }

    // layer 3 A preload (W2 zero-padded to 16 rows); K = 320 = [Y1(64) | X(256)]
    bf16x8 a3[10];
#pragma unroll
    for (int ks = 0; ks < 10; ks++)
        a3[ks] = afrag_bf(wb + WB2_OFF, 320, 0, ks * 32, lane, 5);

    __syncthreads();   // all waves done READING Y0s before Y1 overwrites it

    // ---- epilogue 2 -> Y1 (aliases Y0s) ----
    {
        int m0 = wave * 16 + (rh << 2);
        f32x4 bias = *(const f32x4*)(b1 + m0);
#pragma unroll
        for (int nt = 0; nt < 4; nt++) {
            int nn = nt * 16 + cl;
            float v0 = leaky(acc2[nt][0] + bias[0]);
            float v1 = leaky(acc2[nt][1] + bias[1]);
            float v2 = leaky(acc2[nt][2] + bias[2]);
            float v3 = leaky(acc2[nt][3] + bias[3]);
            int md = (m0 >> 1) ^ ((nn & 7) << 2);
            uint2v pk; pk[0] = pack2(v0, v1); pk[1] = pack2(v2, v3);
            *(uint2v*)(Y0s + nn * 32 + md) = pk;   // Y1 layout: [n][32 dwords]
        }
    }

    __syncthreads();   // LAST barrier — everything after this never drains mid-kernel

    // ---- deferred pf fp32 expansion + store (no later barrier -> drain at retire) ----
    {
        float* pfb = out1 + (size_t)b * C_ * N_ + n0;
        if (okn) {
#pragma unroll
            for (int j = 0; j < 8; j++) {
                int c0 = 4 * (wave * 16 + 2 * j);
                pfb[(size_t)(c0    ) * N_ + lane] = bflo(qa[j][0]);
                pfb[(size_t)(c0 + 1) * N_ + lane] = bfhi(qa[j][0]);
                pfb[(size_t)(c0 + 2) * N_ + lane] = bflo(qa[j][1]);
                pfb[(size_t)(c0 + 3) * N_ + lane] = bfhi(qa[j][1]);
                pfb[(size_t)(c0 + 4) * N_ + lane] = bflo(qb[j][0]);
                pfb[(size_t)(c0 + 5) * N_ + lane] = bfhi(qb[j][0]);
                pfb[(size_t)(c0 + 6) * N_ + lane] = bflo(qb[j][1]);
                pfb[(size_t)(c0 + 7) * N_ + lane] = bfhi(qb[j][1]);
            }
        }
    }

    // ---- layer 3: each wave owns one 16-col N-tile ----
    {
        int nn = wave * 16 + cl;
        f32x4 acc3 = {};
#pragma unroll
        for (int ks = 0; ks < 10; ks++) {
            bf16x8 bx = (ks < 2) ? bfrag(Y0s, 32, nn, ks * 32 + kq)
                                 : bfrag(Xs, 128, nn, (ks - 2) * 32 + kq);
            acc3 = __builtin_amdgcn_mfma_f32_16x16x32_bf16(a3[ks], bx, acc3, 0, 0, 0);
        }
        int gn2 = n0 + nn;
        if (gn2 < N_) {
#pragma unroll
            for (int r2 = 0; r2 < 4; r2++) {
                int m = (rh << 2) + r2;
                if (m < 5) {
                    float v = acc3[r2] + b2[m];
                    v = v > 0.f ? v : 0.f;   // final relu
                    out0[((size_t)b * 5 + m) * N_ + gn2] = v;
                }
            }
        }
    }
}

// ===================== fallback path (round-4): gather + mlp ========================
__global__ __launch_bounds__(512, 6) void gather_kernel(
    const float* __restrict__ points, const float* __restrict__ im,
    float* __restrict__ out1) {
    __shared__ float Lg[HW_ * 4];
    const int t   = threadIdx.x;
    const int bid = blockIdx.x;
    const int b  = ((bid & 7) << 3) | ((bid >> 3) & 7);
    const int ch = bid >> 6;
    const f32x4* im4 = (const f32x4*)(im + ((size_t)b * C_ + ch * 4) * HW_);
#pragma unroll
    for (int g0 = 0; g0 < 2; g0++) {
        int g = t + (g0 << 9);
        if (g < 784) {
            f32x4 r0 = im4[g], r1 = im4[784 + g], r2 = im4[1568 + g], r3 = im4[2352 + g];
#pragma unroll
            for (int i = 0; i < 4; i++) {
                f32x4 v; v[0] = r0[i]; v[1] = r1[i]; v[2] = r2[i]; v[3] = r3[i];
                *(f32x4*)(Lg + (pswz((g << 2) + i) << 2)) = v;
            }
        }
    }
    __syncthreads();
    const float* ptb = points + (size_t)b * N_ * 2;
    const size_t ob0 = ((size_t)b * C_ + ch * 4) * N_;
#pragma unroll 2
    for (int p = 0; p < 14; p++) {
        int n = t + (p << 9);
        if (n < N_) {
            f32x2 pt = *(const f32x2*)(ptb + 2 * n);
            float fx = fminf(fmaxf((pt.x + 1.f) * 27.5f, 0.f), 55.f);
            float fy = fminf(fmaxf((pt.y + 1.f) * 27.5f, 0.f), 55.f);
            float x0f = floorf(fx), y0f = floorf(fy);
            int x0 = (int)x0f, y0 = (int)y0f;
            float wx1 = fx - x0f, wy1 = fy - y0f;
            float wx0 = 1.f - wx1, wy0 = 1.f - wy1;
            bool hix = x0 >= W_ - 1;
            int   xb  = hix ? W_ - 2 : x0;
            float wxl = hix ? 0.f : wx0;
            float wxr = hix ? wx0 : wx1;
            int y0c = min(y0, H_ - 1);
            int y1c = min(y0 + 1, H_ - 1);
            float w00 = wy0 * wxl, w01 = wy0 * wxr, w10 = wy1 * wxl, w11 = wy1 * wxr;
            int ia0 = y0c * W_ + xb, ia1 = y1c * W_ + xb;
            f32x4 q00 = *(const f32x4*)(Lg + (pswz(ia0)     << 2));
            f32x4 q01 = *(const f32x4*)(Lg + (pswz(ia0 + 1) << 2));
            f32x4 q10 = *(const f32x4*)(Lg + (pswz(ia1)     << 2));
            f32x4 q11 = *(const f32x4*)(Lg + (pswz(ia1 + 1) << 2));
            out1[ob0 + n]        = w00*q00[0] + w01*q01[0] + w10*q10[0] + w11*q11[0];
            out1[ob0 + N_ + n]   = w00*q00[1] + w01*q01[1] + w10*q10[1] + w11*q11[1];
            out1[ob0 + 2*N_ + n] = w00*q00[2] + w01*q01[2] + w10*q10[2] + w11*q11[2];
            out1[ob0 + 3*N_ + n] = w00*q00[3] + w01*q01[3] + w10*q10[3] + w11*q11[3];
        }
    }
}

__device__ __forceinline__ bf16x8 afrag_f32(const float* __restrict__ wp, int ldk,
                                            int rowbase, int k0, int lane, int nrows) {
    int i = rowbase + (lane & 15);
    int k = k0 + ((lane >> 4) << 3);
    ushort8 u;
    if (i < nrows) {
        const float* s = wp + (size_t)i * ldk + k;
#pragma unroll
        for (int j = 0; j < 8; j++) u[j] = f2bf(s[j]);
    } else {
#pragma unroll
        for (int j = 0; j < 8; j++) u[j] = 0;
    }
    return __builtin_bit_cast(bf16x8, u);
}

__global__ __launch_bounds__(256) void mlp_fallback(
    const float* __restrict__ pf,
    const float* __restrict__ w0, const float* __restrict__ b0_,
    const float* __restrict__ w1, const float* __restrict__ b1,
    const float* __restrict__ w2, const float* __restrict__ b2,
    float* __restrict__ out0) {
    __shared__ unsigned int Xs[64 * 128];
    __shared__ unsigned int Y0s[64 * 64];
    const int t    = threadIdx.x;
    const int lane = t & 63;
    const int wave = t >> 6;
    const int bid  = blockIdx.x;
    const int b    = bid / NTILE;
    const int tile = bid - b * NTILE;
    const int n0   = tile * 64;
    const int nn_g = min(n0 + lane, N_ - 1);
    const int swz  = (lane & 7) << 2;
    const float* pfb = pf + (size_t)b * C_ * N_;
#pragma unroll
    for (int g8 = 0; g8 < 8; g8++) {
        int c0 = wave * 64 + g8 * 8;
        float v[8];
#pragma unroll
        for (int j = 0; j < 8; j++) v[j] = pfb[(size_t)(c0 + j) * N_ + nn_g];
        uint4v pk;
        pk[0] = pack2(v[0], v[1]); pk[1] = pack2(v[2], v[3]);
        pk[2] = pack2(v[4], v[5]); pk[3] = pack2(v[6], v[7]);
        *(uint4v*)(Xs + lane * 128 + ((c0 >> 1) ^ swz)) = pk;
    }
    bf16x8 a1[2][8];
#pragma unroll
    for (int mt = 0; mt < 2; mt++)
#pragma unroll
        for (int ks = 0; ks < 8; ks++)
            a1[mt][ks] = afrag_f32(w0, 256, (wave * 2 + mt) * 16, ks * 32, lane, 1 << 30);
    __syncthreads();
    const int cl = lane & 15;
    const int rh = lane >> 4;
    const int kq = rh << 3;
    f32x4 acc1[2][4] = {};
#pragma unroll
    for (int ks = 0; ks < 8; ks++) {
        bf16x8 bx[4];
#pragma unroll
        for (int nt = 0; nt < 4; nt++)
            bx[nt] = bfrag(Xs, 128, nt * 16 + cl, ks * 32 + kq);
#pragma unroll
        for (int mt = 0; mt < 2; mt++)
#pragma unroll
            for (int nt = 0; nt < 4; nt++)
                acc1[mt][nt] = __builtin_amdgcn_mfma_f32_16x16x32_bf16(
                    a1[mt][ks], bx[nt], acc1[mt][nt], 0, 0, 0);
    }
#pragma unroll
    for (int mt = 0; mt < 2; mt++) {
        int m0 = (wave * 2 + mt) * 16 + (rh << 2);
        f32x4 bias = *(const f32x4*)(b0_ + m0);
#pragma unroll
        for (int nt = 0; nt < 4; nt++) {
            int nn = nt * 16 + cl;
            float v0 = leaky(acc1[mt][nt][0] + bias[0]);
            float v1 = leaky(acc1[mt][nt][1] + bias[1]);
            float v2 = leaky(acc1[mt][nt][2] + bias[2]);
            float v3 = leaky(acc1[mt][nt][3] + bias[3]);
            int md = (m0 >> 1) ^ ((nn & 7) << 2);
            uint2v pk; pk[0] = pack2(v0, v1); pk[1] = pack2(v2, v3);
            *(uint2v*)(Y0s + nn * 64 + md) = pk;
        }
    }
    bf16x8 a2[12];
#pragma unroll
    for (int ks = 0; ks < 12; ks++)
        a2[ks] = afrag_f32(w1, 384, wave * 16, ks * 32, lane, 1 << 30);
    __syncthreads();
    f32x4 acc2[4] = {};
#pragma unroll
    for (int ks = 0; ks < 12; ks++) {
#pragma unroll
        for (int nt = 0; nt < 4; nt++) {
            bf16x8 bx = (ks < 4) ? bfrag(Y0s, 64, nt * 16 + cl, ks * 32 + kq)
                                 : bfrag(Xs, 128, nt * 16 + cl, (ks - 4) * 32 + kq);
            acc2[nt] = __builtin_amdgcn_mfma_f32_16x16x32_bf16(a2[ks], bx, acc2[nt], 0, 0, 0);
        }
    }
    bf16x8 a3[10];
#pragma unroll
    for (int ks = 0; ks < 10; ks++)
        a3[ks] = afrag_f32(w2, 320, 0, ks * 32, lane, 5);
    __syncthreads();
    {
        int m0 = wave * 16 + (rh << 2);
        f32x4 bias = *(const f32x4*)(b1 + m0);
#pragma unroll
        for (int nt = 0; nt < 4; nt++) {
            int nn = nt * 16 + cl;
            float v0 = leaky(acc2[nt][0] + bias[0]);
            float v1 = leaky(acc2[nt][1] + bias[1]);
            float v2 = leaky(acc2[nt][2] + bias[2]);
            float v3 = leaky(acc2[nt][3] + bias[3]);
            int md = (m0 >> 1) ^ ((nn & 7) << 2);
            uint2v pk; pk[0] = pack2(v0, v1); pk[1] = pack2(v2, v3);
            *(uint2v*)(Y0s + nn * 32 + md) = pk;
        }
    }
    __syncthreads();
    {
        int nn = wave * 16 + cl;
        f32x4 acc3 = {};
#pragma unroll
        for (int ks = 0; ks < 10; ks++) {
            bf16x8 bx = (ks < 2) ? bfrag(Y0s, 32, nn, ks * 32 + kq)
                                 : bfrag(Xs, 128, nn, (ks - 2) * 32 + kq);
            acc3 = __builtin_amdgcn_mfma_f32_16x16x32_bf16(a3[ks], bx, acc3, 0, 0, 0);
        }
        int gn2 = n0 + nn;
        if (gn2 < N_) {
#pragma unroll
            for (int r2 = 0; r2 < 4; r2++) {
                int m = (rh << 2) + r2;
                if (m < 5) {
                    float v = acc3[r2] + b2[m];
                    v = v > 0.f ? v : 0.f;
                    out0[((size_t)b * 5 + m) * N_ + gn2] = v;
                }
            }
        }
    }
}

extern "C" void kernel_launch(void* const* d_in, const int* in_sizes, int n_in,
                              void* d_out, int out_size, void* d_ws, size_t ws_size,
                              hipStream_t stream) {
    const float* points = (const float*)d_in[0];
    const float* im     = (const float*)d_in[1];
    const float* w0     = (const float*)d_in[2];
    const float* b0     = (const float*)d_in[3];
    const float* w1     = (const float*)d_in[4];
    const float* b1     = (const float*)d_in[5];
    const float* w2     = (const float*)d_in[6];
    const float* b2     = (const float*)d_in[7];
    float* out0 = (float*)d_out;                   // mesh_align_feat [64][5*6890]
    float* out1 = out0 + (size_t)B_ * 5 * N_;      // point_feat      [64][256][6890]

    const size_t XBYTES = (size_t)B_ * 64 * N_ * 8;   // x2 bf16: 64 chunks x uint2, 225.8 MB
    const size_t WBYTES = (size_t)WTOT * 2;
    const bool cok = (d_ws != nullptr) && (ws_size >= XBYTES + WBYTES);
    unsigned int*   x2 = (unsigned int*)d_ws;
    unsigned short* wb = (unsigned short*)((char*)d_ws + XBYTES);

    if (cok) {
        hipLaunchKernelGGL(wconv_kernel, dim3((WTOT + 255) / 256), dim3(256), 0, stream,
                           w0, w1, w2, wb);
        hipLaunchKernelGGL(gather_c, dim3(B_ * 64), dim3(512), 0, stream,
                           points, im, x2);
        hipLaunchKernelGGL(mlp_c, dim3(B_ * NTILE), dim3(256), 0, stream,
                           x2, b0, b1, b2, wb, out0, out1);
    } else {
        hipLaunchKernelGGL(gather_kernel, dim3(B_ * 64), dim3(512), 0, stream,
                           points, im, out1);
        hipLaunchKernelGGL(mlp_fallback, dim3(B_ * NTILE), dim3(256), 0, stream,
                           out1, w0, b0, w1, b1, w2, b2, out0);
    }
}

// Round 9
// 346.149 us; speedup vs baseline: 1.1354x; 1.0276x over previous
//
#include <hip/hip_runtime.h>

#define B_    64
#define C_    256
#define H_    56
#define W_    56
#define N_    6890
#define HW_   3136
#define NTILE 108          // ceil(6890/64) MLP point tiles

#define WB1_OFF (128*256)
#define WB2_OFF (128*256 + 64*384)
#define WTOT    (128*256 + 64*384 + 5*320)   // 58944 bf16 weight elements

typedef __attribute__((ext_vector_type(8))) __bf16 bf16x8;
typedef __attribute__((ext_vector_type(8))) unsigned short ushort8;
typedef __attribute__((ext_vector_type(4))) float f32x4;
typedef __attribute__((ext_vector_type(2))) float f32x2;
typedef __attribute__((ext_vector_type(4))) unsigned int uint4v;
typedef __attribute__((ext_vector_type(2))) unsigned int uint2v;

__device__ __forceinline__ unsigned short f2bf(float f) {
    unsigned int u = __builtin_bit_cast(unsigned int, f);
    u += 0x7FFFu + ((u >> 16) & 1u);   // RTNE
    return (unsigned short)(u >> 16);
}
__device__ __forceinline__ unsigned int pack2(float lo, float hi) {
    return (unsigned int)f2bf(lo) | ((unsigned int)f2bf(hi) << 16);
}
__device__ __forceinline__ float leaky(float v) { return v > 0.f ? v : 0.01f * v; }
__device__ __forceinline__ int pswz(int p) { return p ^ ((p >> 3) & 7); }

// ============================ kernel 0: weight bf16 pack ============================
__global__ void wconv_kernel(const float* __restrict__ w0, const float* __restrict__ w1,
                             const float* __restrict__ w2, unsigned short* __restrict__ wb) {
    int i = blockIdx.x * 256 + threadIdx.x;
    if (i >= WTOT) return;
    float v = (i < WB1_OFF) ? w0[i] : (i < WB2_OFF) ? w1[i - WB1_OFF] : w2[i - WB2_OFF];
    wb[i] = f2bf(v);
}

// ============== kernel 1: bilinear gather -> pf fp32 AND x2 bf16 ====================
// One block per (batch, 4-channel chunk). Stage 4 planes (50 KB) to LDS once
// (image read from HBM exactly once, coalesced); LDS [pixel(swizzled)][4ch] ->
// each bilinear corner is one ds_read_b128. 24 waves/CU streaming: ALL bulk
// writes live here (pf 451 MB + x2 226 MB), both coalesced over consecutive n.
__global__ __launch_bounds__(512, 6) void gather_bx(
    const float* __restrict__ points, const float* __restrict__ im,
    float* __restrict__ pf, unsigned int* __restrict__ x2) {
    __shared__ float Ls[HW_ * 4];   // 50176 B

    const int t   = threadIdx.x;
    const int bid = blockIdx.x;
    const int b  = ((bid & 7) << 3) | ((bid >> 3) & 7);   // batch pinned to XCD bid&7
    const int ch = bid >> 6;                              // 0..63 chunk

    // ---- stage 4 planes, transposing to [pixel][4ch] with pixel swizzle ----
    const f32x4* im4 = (const f32x4*)(im + ((size_t)b * C_ + ch * 4) * HW_);
#pragma unroll
    for (int g0 = 0; g0 < 2; g0++) {
        int g = t + (g0 << 9);
        if (g < 784) {
            f32x4 r0 = im4[g], r1 = im4[784 + g], r2 = im4[1568 + g], r3 = im4[2352 + g];
#pragma unroll
            for (int i = 0; i < 4; i++) {
                f32x4 v; v[0] = r0[i]; v[1] = r1[i]; v[2] = r2[i]; v[3] = r3[i];
                *(f32x4*)(Ls + (pswz((g << 2) + i) << 2)) = v;
            }
        }
    }
    __syncthreads();

    // ---- gather all points for these 4 channels; emit pf fp32 + x2 bf16 ----
    const float* ptb = points + (size_t)b * N_ * 2;
    const size_t ob0 = ((size_t)b * C_ + ch * 4) * N_;
    unsigned int* xout = x2 + ((size_t)((b << 6) + ch) * N_) * 2;
#pragma unroll 2
    for (int p = 0; p < 14; p++) {            // 14*512 >= 6890
        int n = t + (p << 9);
        if (n < N_) {
            f32x2 pt = *(const f32x2*)(ptb + 2 * n);
            float fx = fminf(fmaxf((pt.x + 1.f) * 27.5f, 0.f), 55.f);
            float fy = fminf(fmaxf((pt.y + 1.f) * 27.5f, 0.f), 55.f);
            float x0f = floorf(fx), y0f = floorf(fy);
            int x0 = (int)x0f, y0 = (int)y0f;
            float wx1 = fx - x0f, wy1 = fy - y0f;
            float wx0 = 1.f - wx1, wy0 = 1.f - wy1;
            bool hix = x0 >= W_ - 1;          // fx==55 edge: weight moves to right tap
            int   xb  = hix ? W_ - 2 : x0;
            float wxl = hix ? 0.f : wx0;
            float wxr = hix ? wx0 : wx1;
            int y0c = min(y0, H_ - 1);
            int y1c = min(y0 + 1, H_ - 1);    // fy==55 edge: wy1==0
            float w00 = wy0 * wxl, w01 = wy0 * wxr;
            float w10 = wy1 * wxl, w11 = wy1 * wxr;
            int ia0 = y0c * W_ + xb, ia1 = y1c * W_ + xb;

            f32x4 q00 = *(const f32x4*)(Ls + (pswz(ia0)     << 2));
            f32x4 q01 = *(const f32x4*)(Ls + (pswz(ia0 + 1) << 2));
            f32x4 q10 = *(const f32x4*)(Ls + (pswz(ia1)     << 2));
            f32x4 q11 = *(const f32x4*)(Ls + (pswz(ia1 + 1) << 2));
            float v0 = w00*q00[0] + w01*q01[0] + w10*q10[0] + w11*q11[0];
            float v1 = w00*q00[1] + w01*q01[1] + w10*q10[1] + w11*q11[1];
            float v2 = w00*q00[2] + w01*q01[2] + w10*q10[2] + w11*q11[2];
            float v3 = w00*q00[3] + w01*q01[3] + w10*q10[3] + w11*q11[3];
            pf[ob0 + n]          = v0;        // coalesced over lanes (consecutive n)
            pf[ob0 + N_ + n]     = v1;
            pf[ob0 + 2*N_ + n]   = v2;
            pf[ob0 + 3*N_ + n]   = v3;
            uint2v pk; pk[0] = pack2(v0, v1); pk[1] = pack2(v2, v3);
            *(uint2v*)(xout + (size_t)n * 2) = pk;   // coalesced 8B over consecutive n
        }
    }
}

// ================= kernel 2: lean MFMA MLP (x2 in, mesh out ONLY) ===================
__device__ __forceinline__ bf16x8 afrag_bf(const unsigned short* __restrict__ wb, int ldk,
                                           int rowbase, int k0, int lane, int nrows) {
    int i = rowbase + (lane & 15);
    int k = k0 + ((lane >> 4) << 3);
    if (i < nrows) return __builtin_bit_cast(bf16x8, *(const ushort8*)(wb + (size_t)i * ldk + k));
    ushort8 z = {0, 0, 0, 0, 0, 0, 0, 0};
    return __builtin_bit_cast(bf16x8, z);
}
// B-fragment from swizzled LDS: buf[n][cd ^ ((n&7)<<2)], 4 dwords at k0
__device__ __forceinline__ bf16x8 bfrag(const unsigned int* buf, int rowstride_dw,
                                        int n, int k0) {
    int cd = (k0 >> 1) ^ ((n & 7) << 2);
    uint4v v = *(const uint4v*)(buf + n * rowstride_dw + cd);
    return __builtin_bit_cast(bf16x8, v);
}

__global__ __launch_bounds__(256) void mlp_x(
    const unsigned int* __restrict__ x2,
    const float* __restrict__ b0_, const float* __restrict__ b1,
    const float* __restrict__ b2, const unsigned short* __restrict__ wb,
    float* __restrict__ out0) {
    __shared__ unsigned int Xs[64 * 128];   // X  [n=64][c=256] bf16, swizzled (32KB)
    __shared__ unsigned int Y0s[64 * 64];   // Y0 [n][m=128] bf16 (16KB); Y1 aliased in

    const int t    = threadIdx.x;
    const int lane = t & 63;
    const int wave = t >> 6;
    const int bid  = blockIdx.x;
    const int b    = bid / NTILE;
    const int tile = bid - b * NTILE;
    const int n0   = tile * 64;

    const int nn_g = min(n0 + lane, N_ - 1);
    const int swz  = (lane & 7) << 2;

    // ---- stage X from x2: 16 b64 coalesced loads + 8 b128 LDS writes ----
#pragma unroll
    for (int j = 0; j < 8; j++) {
        int d2a = wave * 16 + 2 * j;                         // chunk pair base
        const unsigned int* src = x2 + ((size_t)((b << 6) + d2a) * N_ + nn_g) * 2;
        uint2v q0 = *(const uint2v*)src;
        uint2v q1 = *(const uint2v*)(src + 2 * (size_t)N_);
        uint4v pk; pk[0] = q0[0]; pk[1] = q0[1]; pk[2] = q1[0]; pk[3] = q1[1];
        *(uint4v*)(Xs + lane * 128 + ((wave * 32 + 4 * j) ^ swz)) = pk;
    }

    // ---- layer 1 A preload ----
    bf16x8 a1[2][8];
#pragma unroll
    for (int mt = 0; mt < 2; mt++)
#pragma unroll
        for (int ks = 0; ks < 8; ks++)
            a1[mt][ks] = afrag_bf(wb, 256, (wave * 2 + mt) * 16, ks * 32, lane, 1 << 30);

    __syncthreads();

    const int cl = lane & 15;
    const int rh = lane >> 4;
    const int kq = rh << 3;

    // ---- layer 1: Y0[128,64] = leaky(W0 @ X + b0) ----
    f32x4 acc1[2][4] = {};
#pragma unroll
    for (int ks = 0; ks < 8; ks++) {
        bf16x8 bx[4];
#pragma unroll
        for (int nt = 0; nt < 4; nt++)
            bx[nt] = bfrag(Xs, 128, nt * 16 + cl, ks * 32 + kq);
#pragma unroll
        for (int mt = 0; mt < 2; mt++)
#pragma unroll
            for (int nt = 0; nt < 4; nt++)
                acc1[mt][nt] = __builtin_amdgcn_mfma_f32_16x16x32_bf16(
                    a1[mt][ks], bx[nt], acc1[mt][nt], 0, 0, 0);
    }

#pragma unroll
    for (int mt = 0; mt < 2; mt++) {
        int m0 = (wave * 2 + mt) * 16 + (rh << 2);
        f32x4 bias = *(const f32x4*)(b0_ + m0);
#pragma unroll
        for (int nt = 0; nt < 4; nt++) {
            int nn = nt * 16 + cl;
            float v0 = leaky(acc1[mt][nt][0] + bias[0]);
            float v1 = leaky(acc1[mt][nt][1] + bias[1]);
            float v2 = leaky(acc1[mt][nt][2] + bias[2]);
            float v3 = leaky(acc1[mt][nt][3] + bias[3]);
            int md = (m0 >> 1) ^ ((nn & 7) << 2);
            uint2v pk; pk[0] = pack2(v0, v1); pk[1] = pack2(v2, v3);
            *(uint2v*)(Y0s + nn * 64 + md) = pk;
        }
    }

    // ---- layer 2 A preload: K = 384 = [Y0(128) | X(256)] ----
    bf16x8 a2[12];
#pragma unroll
    for (int ks = 0; ks < 12; ks++)
        a2[ks] = afrag_bf(wb + WB1_OFF, 384, wave * 16, ks * 32, lane, 1 << 30);

    __syncthreads();

    f32x4 acc2[4] = {};
#pragma unroll
    for (int ks = 0; ks < 12; ks++) {
#pragma unroll
        for (int nt = 0; nt < 4; nt++) {
            bf16x8 bx = (ks < 4) ? bfrag(Y0s, 64, nt * 16 + cl, ks * 32 + kq)
                                 : bfrag(Xs, 128, nt * 16 + cl, (ks - 4) * 32 + kq);
            acc2[nt] = __builtin_amdgcn_mfma_f32_16x16x32_bf16(a2[ks], bx, acc2[nt], 0, 0, 0);
        }
    }

    // layer 3 A preload (W2 zero-padded to 16 rows); K = 320 = [Y1(64) | X(256)]
    bf16x8 a3[10];
#pragma unroll
    for (int ks = 0; ks < 10; ks++)
        a3[ks] = afrag_bf(wb + WB2_OFF, 320, 0, ks * 32, lane, 5);

    __syncthreads();   // all waves done READING Y0s before Y1 overwrites it

    // ---- epilogue 2 -> Y1 (aliases Y0s) ----
    {
        int m0 = wave * 16 + (rh << 2);
        f32x4 bias = *(const f32x4*)(b1 + m0);
#pragma unroll
        for (int nt = 0; nt < 4; nt++) {
            int nn = nt * 16 + cl;
            float v0 = leaky(acc2[nt][0] + bias[0]);
            float v1 = leaky(acc2[nt][1] + bias[1]);
            float v2 = leaky(acc2[nt][2] + bias[2]);
            float v3 = leaky(acc2[nt][3] + bias[3]);
            int md = (m0 >> 1) ^ ((nn & 7) << 2);
            uint2v pk; pk[0] = pack2(v0, v1); pk[1] = pack2(v2, v3);
            *(uint2v*)(Y0s + nn * 32 + md) = pk;   // Y1 layout: [n][32 dwords]
        }
    }

    __syncthreads();

    // ---- layer 3: each wave owns one 16-col N-tile ----
    {
        int nn = wave * 16 + cl;
        f32x4 acc3 = {};
#pragma unroll
        for (int ks = 0; ks < 10; ks++) {
            bf16x8 bx = (ks < 2) ? bfrag(Y0s, 32, nn, ks * 32 + kq)
                                 : bfrag(Xs, 128, nn, (ks - 2) * 32 + kq);
            acc3 = __builtin_amdgcn_mfma_f32_16x16x32_bf16(a3[ks], bx, acc3, 0, 0, 0);
        }
        int gn2 = n0 + nn;
        if (gn2 < N_) {
#pragma unroll
            for (int r2 = 0; r2 < 4; r2++) {
                int m = (rh << 2) + r2;
                if (m < 5) {
                    float v = acc3[r2] + b2[m];
                    v = v > 0.f ? v : 0.f;   // final relu
                    out0[((size_t)b * 5 + m) * N_ + gn2] = v;
                }
            }
        }
    }
}

// ===================== fallback path (round-4): gather + mlp ========================
__device__ __forceinline__ bf16x8 afrag_f32(const float* __restrict__ wp, int ldk,
                                            int rowbase, int k0, int lane, int nrows) {
    int i = rowbase + (lane & 15);
    int k = k0 + ((lane >> 4) << 3);
    ushort8 u;
    if (i < nrows) {
        const float* s = wp + (size_t)i * ldk + k;
#pragma unroll
        for (int j = 0; j < 8; j++) u[j] = f2bf(s[j]);
    } else {
#pragma unroll
        for (int j = 0; j < 8; j++) u[j] = 0;
    }
    return __builtin_bit_cast(bf16x8, u);
}

__global__ __launch_bounds__(512, 6) void gather_kernel(
    const float* __restrict__ points, const float* __restrict__ im,
    float* __restrict__ out1) {
    __shared__ float Lg[HW_ * 4];
    const int t   = threadIdx.x;
    const int bid = blockIdx.x;
    const int b  = ((bid & 7) << 3) | ((bid >> 3) & 7);
    const int ch = bid >> 6;
    const f32x4* im4 = (const f32x4*)(im + ((size_t)b * C_ + ch * 4) * HW_);
#pragma unroll
    for (int g0 = 0; g0 < 2; g0++) {
        int g = t + (g0 << 9);
        if (g < 784) {
            f32x4 r0 = im4[g], r1 = im4[784 + g], r2 = im4[1568 + g], r3 = im4[2352 + g];
#pragma unroll
            for (int i = 0; i < 4; i++) {
                f32x4 v; v[0] = r0[i]; v[1] = r1[i]; v[2] = r2[i]; v[3] = r3[i];
                *(f32x4*)(Lg + (pswz((g << 2) + i) << 2)) = v;
            }
        }
    }
    __syncthreads();
    const float* ptb = points + (size_t)b * N_ * 2;
    const size_t ob0 = ((size_t)b * C_ + ch * 4) * N_;
#pragma unroll 2
    for (int p = 0; p < 14; p++) {
        int n = t + (p << 9);
        if (n < N_) {
            f32x2 pt = *(const f32x2*)(ptb + 2 * n);
            float fx = fminf(fmaxf((pt.x + 1.f) * 27.5f, 0.f), 55.f);
            float fy = fminf(fmaxf((pt.y + 1.f) * 27.5f, 0.f), 55.f);
            float x0f = floorf(fx), y0f = floorf(fy);
            int x0 = (int)x0f, y0 = (int)y0f;
            float wx1 = fx - x0f, wy1 = fy - y0f;
            float wx0 = 1.f - wx1, wy0 = 1.f - wy1;
            bool hix = x0 >= W_ - 1;
            int   xb  = hix ? W_ - 2 : x0;
            float wxl = hix ? 0.f : wx0;
            float wxr = hix ? wx0 : wx1;
            int y0c = min(y0, H_ - 1);
            int y1c = min(y0 + 1, H_ - 1);
            float w00 = wy0 * wxl, w01 = wy0 * wxr, w10 = wy1 * wxl, w11 = wy1 * wxr;
            int ia0 = y0c * W_ + xb, ia1 = y1c * W_ + xb;
            f32x4 q00 = *(const f32x4*)(Lg + (pswz(ia0)     << 2));
            f32x4 q01 = *(const f32x4*)(Lg + (pswz(ia0 + 1) << 2));
            f32x4 q10 = *(const f32x4*)(Lg + (pswz(ia1)     << 2));
            f32x4 q11 = *(const f32x4*)(Lg + (pswz(ia1 + 1) << 2));
            out1[ob0 + n]        = w00*q00[0] + w01*q01[0] + w10*q10[0] + w11*q11[0];
            out1[ob0 + N_ + n]   = w00*q00[1] + w01*q01[1] + w10*q10[1] + w11*q11[1];
            out1[ob0 + 2*N_ + n] = w00*q00[2] + w01*q01[2] + w10*q10[2] + w11*q11[2];
            out1[ob0 + 3*N_ + n] = w00*q00[3] + w01*q01[3] + w10*q10[3] + w11*q11[3];
        }
    }
}

__global__ __launch_bounds__(256) void mlp_fallback(
    const float* __restrict__ pf,
    const float* __restrict__ w0, const float* __restrict__ b0_,
    const float* __restrict__ w1, const float* __restrict__ b1,
    const float* __restrict__ w2, const float* __restrict__ b2,
    float* __restrict__ out0) {
    __shared__ unsigned int Xs[64 * 128];
    __shared__ unsigned int Y0s[64 * 64];
    const int t    = threadIdx.x;
    const int lane = t & 63;
    const int wave = t >> 6;
    const int bid  = blockIdx.x;
    const int b    = bid / NTILE;
    const int tile = bid - b * NTILE;
    const int n0   = tile * 64;
    const int nn_g = min(n0 + lane, N_ - 1);
    const int swz  = (lane & 7) << 2;
    const float* pfb = pf + (size_t)b * C_ * N_;
#pragma unroll
    for (int g8 = 0; g8 < 8; g8++) {
        int c0 = wave * 64 + g8 * 8;
        float v[8];
#pragma unroll
        for (int j = 0; j < 8; j++) v[j] = pfb[(size_t)(c0 + j) * N_ + nn_g];
        uint4v pk;
        pk[0] = pack2(v[0], v[1]); pk[1] = pack2(v[2], v[3]);
        pk[2] = pack2(v[4], v[5]); pk[3] = pack2(v[6], v[7]);
        *(uint4v*)(Xs + lane * 128 + ((c0 >> 1) ^ swz)) = pk;
    }
    bf16x8 a1[2][8];
#pragma unroll
    for (int mt = 0; mt < 2; mt++)
#pragma unroll
        for (int ks = 0; ks < 8; ks++)
            a1[mt][ks] = afrag_f32(w0, 256, (wave * 2 + mt) * 16, ks * 32, lane, 1 << 30);
    __syncthreads();
    const int cl = lane & 15;
    const int rh = lane >> 4;
    const int kq = rh << 3;
    f32x4 acc1[2][4] = {};
#pragma unroll
    for (int ks = 0; ks < 8; ks++) {
        bf16x8 bx[4];
#pragma unroll
        for (int nt = 0; nt < 4; nt++)
            bx[nt] = bfrag(Xs, 128, nt * 16 + cl, ks * 32 + kq);
#pragma unroll
        for (int mt = 0; mt < 2; mt++)
#pragma unroll
            for (int nt = 0; nt < 4; nt++)
                acc1[mt][nt] = __builtin_amdgcn_mfma_f32_16x16x32_bf16(
                    a1[mt][ks], bx[nt], acc1[mt][nt], 0, 0, 0);
    }
#pragma unroll
    for (int mt = 0; mt < 2; mt++) {
        int m0 = (wave * 2 + mt) * 16 + (rh << 2);
        f32x4 bias = *(const f32x4*)(b0_ + m0);
#pragma unroll
        for (int nt = 0; nt < 4; nt++) {
            int nn = nt * 16 + cl;
            float v0 = leaky(acc1[mt][nt][0] + bias[0]);
            float v1 = leaky(acc1[mt][nt][1] + bias[1]);
            float v2 = leaky(acc1[mt][nt][2] + bias[2]);
            float v3 = leaky(acc1[mt][nt][3] + bias[3]);
            int md = (m0 >> 1) ^ ((nn & 7) << 2);
            uint2v pk; pk[0] = pack2(v0, v1); pk[1] = pack2(v2, v3);
            *(uint2v*)(Y0s + nn * 64 + md) = pk;
        }
    }
    bf16x8 a2[12];
#pragma unroll
    for (int ks = 0; ks < 12; ks++)
        a2[ks] = afrag_f32(w1, 384, wave * 16, ks * 32, lane, 1 << 30);
    __syncthreads();
    f32x4 acc2[4] = {};
#pragma unroll
    for (int ks = 0; ks < 12; ks++) {
#pragma unroll
        for (int nt = 0; nt < 4; nt++) {
            bf16x8 bx = (ks < 4) ? bfrag(Y0s, 64, nt * 16 + cl, ks * 32 + kq)
                                 : bfrag(Xs, 128, nt * 16 + cl, (ks - 4) * 32 + kq);
            acc2[nt] = __builtin_amdgcn_mfma_f32_16x16x32_bf16(a2[ks], bx, acc2[nt], 0, 0, 0);
        }
    }
    bf16x8 a3[10];
#pragma unroll
    for (int ks = 0; ks < 10; ks++)
        a3[ks] = afrag_f32(w2, 320, 0, ks * 32, lane, 5);
    __syncthreads();
    {
        int m0 = wave * 16 + (rh << 2);
        f32x4 bias = *(const f32x4*)(b1 + m0);
#pragma unroll
        for (int nt = 0; nt < 4; nt++) {
            int nn = nt * 16 + cl;
            float v0 = leaky(acc2[nt][0] + bias[0]);
            float v1 = leaky(acc2[nt][1] + bias[1]);
            float v2 = leaky(acc2[nt][2] + bias[2]);
            float v3 = leaky(acc2[nt][3] + bias[3]);
            int md = (m0 >> 1) ^ ((nn & 7) << 2);
            uint2v pk; pk[0] = pack2(v0, v1); pk[1] = pack2(v2, v3);
            *(uint2v*)(Y0s + nn * 32 + md) = pk;
        }
    }
    __syncthreads();
    {
        int nn = wave * 16 + cl;
        f32x4 acc3 = {};
#pragma unroll
        for (int ks = 0; ks < 10; ks++) {
            bf16x8 bx = (ks < 2) ? bfrag(Y0s, 32, nn, ks * 32 + kq)
                                 : bfrag(Xs, 128, nn, (ks - 2) * 32 + kq);
            acc3 = __builtin_amdgcn_mfma_f32_16x16x32_bf16(a3[ks], bx, acc3, 0, 0, 0);
        }
        int gn2 = n0 + nn;
        if (gn2 < N_) {
#pragma unroll
            for (int r2 = 0; r2 < 4; r2++) {
                int m = (rh << 2) + r2;
                if (m < 5) {
                    float v = acc3[r2] + b2[m];
                    v = v > 0.f ? v : 0.f;
                    out0[((size_t)b * 5 + m) * N_ + gn2] = v;
                }
            }
        }
    }
}

extern "C" void kernel_launch(void* const* d_in, const int* in_sizes, int n_in,
                              void* d_out, int out_size, void* d_ws, size_t ws_size,
                              hipStream_t stream) {
    const float* points = (const float*)d_in[0];
    const float* im     = (const float*)d_in[1];
    const float* w0     = (const float*)d_in[2];
    const float* b0     = (const float*)d_in[3];
    const float* w1     = (const float*)d_in[4];
    const float* b1     = (const float*)d_in[5];
    const float* w2     = (const float*)d_in[6];
    const float* b2     = (const float*)d_in[7];
    float* out0 = (float*)d_out;                   // mesh_align_feat [64][5*6890]
    float* out1 = out0 + (size_t)B_ * 5 * N_;      // point_feat      [64][256][6890]

    const size_t XBYTES = (size_t)B_ * 64 * N_ * 8;   // x2 bf16: 64 chunks x uint2, 225.8 MB
    const size_t WBYTES = (size_t)WTOT * 2;
    const bool cok = (d_ws != nullptr) && (ws_size >= XBYTES + WBYTES);
    unsigned int*   x2 = (unsigned int*)d_ws;
    unsigned short* wb = (unsigned short*)((char*)d_ws + XBYTES);

    if (cok) {
        hipLaunchKernelGGL(wconv_kernel, dim3((WTOT + 255) / 256), dim3(256), 0, stream,
                           w0, w1, w2, wb);
        hipLaunchKernelGGL(gather_bx, dim3(B_ * 64), dim3(512), 0, stream,
                           points, im, out1, x2);
        hipLaunchKernelGGL(mlp_x, dim3(B_ * NTILE), dim3(256), 0, stream,
                           x2, b0, b1, b2, wb, out0);
    } else {
        hipLaunchKernelGGL(gather_kernel, dim3(B_ * 64), dim3(512), 0, stream,
                           points, im, out1);
        hipLaunchKernelGGL(mlp_fallback, dim3(B_ * NTILE), dim3(256), 0, stream,
                           out1, w0, b0, w1, b1, w2, b2, out0);
    }
}

// Round 11
// 329.427 us; speedup vs baseline: 1.1931x; 1.0508x over previous
//
#include <hip/hip_runtime.h>

#define B_    64
#define C_    256
#define H_    56
#define W_    56
#define N_    6890
#define HW_   3136
#define NTILE 108          // ceil(6890/64) MLP point tiles

#define WB1_OFF (128*256)
#define WB2_OFF (128*256 + 64*384)
#define WTOT    (128*256 + 64*384 + 5*320)   // 58944 bf16 weight elements

typedef __attribute__((ext_vector_type(8))) __bf16 bf16x8;
typedef __attribute__((ext_vector_type(8))) unsigned short ushort8;
typedef __attribute__((ext_vector_type(4))) float f32x4;
typedef __attribute__((ext_vector_type(2))) float f32x2;
typedef __attribute__((ext_vector_type(4))) unsigned int uint4v;
typedef __attribute__((ext_vector_type(2))) unsigned int uint2v;

__device__ __forceinline__ unsigned short f2bf(float f) {
    unsigned int u = __builtin_bit_cast(unsigned int, f);
    u += 0x7FFFu + ((u >> 16) & 1u);   // RTNE
    return (unsigned short)(u >> 16);
}
__device__ __forceinline__ unsigned int pack2(float lo, float hi) {
    return (unsigned int)f2bf(lo) | ((unsigned int)f2bf(hi) << 16);
}
__device__ __forceinline__ float leaky(float v) { return v > 0.f ? v : 0.01f * v; }
__device__ __forceinline__ int pswz(int p) { return p ^ ((p >> 3) & 7); }

// ============================ kernel 0: weight bf16 pack ============================
__global__ void wconv_kernel(const float* __restrict__ w0, const float* __restrict__ w1,
                             const float* __restrict__ w2, unsigned short* __restrict__ wb) {
    int i = blockIdx.x * 256 + threadIdx.x;
    if (i >= WTOT) return;
    float v = (i < WB1_OFF) ? w0[i] : (i < WB2_OFF) ? w1[i - WB1_OFF] : w2[i - WB2_OFF];
    wb[i] = f2bf(v);
}

// ===================== kernel 1: bilinear gather -> pf fp32 =========================
// One block per (batch, 4-channel chunk): 4096 blocks x 512 threads, 24 waves/CU.
// Stage 4 planes (50 KB) to LDS once (image read from HBM exactly once, coalesced);
// LDS [pixel(swizzled)][4ch] -> each bilinear corner is one ds_read_b128.
__global__ __launch_bounds__(512, 6) void gather_kernel(
    const float* __restrict__ points, const float* __restrict__ im,
    float* __restrict__ out1) {
    __shared__ float Ls[HW_ * 4];   // 50176 B

    const int t   = threadIdx.x;
    const int bid = blockIdx.x;
    const int b  = ((bid & 7) << 3) | ((bid >> 3) & 7);   // batch pinned to XCD bid&7
    const int ch = bid >> 6;                              // 0..63 chunk

    const f32x4* im4 = (const f32x4*)(im + ((size_t)b * C_ + ch * 4) * HW_);
#pragma unroll
    for (int g0 = 0; g0 < 2; g0++) {
        int g = t + (g0 << 9);
        if (g < 784) {
            f32x4 r0 = im4[g], r1 = im4[784 + g], r2 = im4[1568 + g], r3 = im4[2352 + g];
#pragma unroll
            for (int i = 0; i < 4; i++) {
                f32x4 v; v[0] = r0[i]; v[1] = r1[i]; v[2] = r2[i]; v[3] = r3[i];
                *(f32x4*)(Ls + (pswz((g << 2) + i) << 2)) = v;
            }
        }
    }
    __syncthreads();

    const float* ptb = points + (size_t)b * N_ * 2;
    const size_t ob0 = ((size_t)b * C_ + ch * 4) * N_;
#pragma unroll 2
    for (int p = 0; p < 14; p++) {            // 14*512 >= 6890
        int n = t + (p << 9);
        if (n < N_) {
            f32x2 pt = *(const f32x2*)(ptb + 2 * n);
            float fx = fminf(fmaxf((pt.x + 1.f) * 27.5f, 0.f), 55.f);
            float fy = fminf(fmaxf((pt.y + 1.f) * 27.5f, 0.f), 55.f);
            float x0f = floorf(fx), y0f = floorf(fy);
            int x0 = (int)x0f, y0 = (int)y0f;
            float wx1 = fx - x0f, wy1 = fy - y0f;
            float wx0 = 1.f - wx1, wy0 = 1.f - wy1;
            bool hix = x0 >= W_ - 1;          // fx==55 edge: weight moves to right tap
            int   xb  = hix ? W_ - 2 : x0;
            float wxl = hix ? 0.f : wx0;
            float wxr = hix ? wx0 : wx1;
            int y0c = min(y0, H_ - 1);
            int y1c = min(y0 + 1, H_ - 1);    // fy==55 edge: wy1==0
            float w00 = wy0 * wxl, w01 = wy0 * wxr;
            float w10 = wy1 * wxl, w11 = wy1 * wxr;
            int ia0 = y0c * W_ + xb, ia1 = y1c * W_ + xb;

            f32x4 q00 = *(const f32x4*)(Ls + (pswz(ia0)     << 2));
            f32x4 q01 = *(const f32x4*)(Ls + (pswz(ia0 + 1) << 2));
            f32x4 q10 = *(const f32x4*)(Ls + (pswz(ia1)     << 2));
            f32x4 q11 = *(const f32x4*)(Ls + (pswz(ia1 + 1) << 2));
            out1[ob0 + n]          = w00*q00[0] + w01*q01[0] + w10*q10[0] + w11*q11[0];
            out1[ob0 + N_ + n]     = w00*q00[1] + w01*q01[1] + w10*q10[1] + w11*q11[1];
            out1[ob0 + 2*N_ + n]   = w00*q00[2] + w01*q01[2] + w10*q10[2] + w11*q11[2];
            out1[ob0 + 3*N_ + n]   = w00*q00[3] + w01*q01[3] + w10*q10[3] + w11*q11[3];
        }
    }
}

// ============================ kernel 2: MFMA MLP ====================================
__device__ __forceinline__ bf16x8 afrag_f32(const float* __restrict__ wp, int ldk,
                                            int rowbase, int k0, int lane, int nrows) {
    int i = rowbase + (lane & 15);
    int k = k0 + ((lane >> 4) << 3);
    ushort8 u;
    if (i < nrows) {
        const float* s = wp + (size_t)i * ldk + k;
#pragma unroll
        for (int j = 0; j < 8; j++) u[j] = f2bf(s[j]);
    } else {
#pragma unroll
        for (int j = 0; j < 8; j++) u[j] = 0;
    }
    return __builtin_bit_cast(bf16x8, u);
}
__device__ __forceinline__ bf16x8 afrag_bf(const unsigned short* __restrict__ wb, int ldk,
                                           int rowbase, int k0, int lane, int nrows) {
    int i = rowbase + (lane & 15);
    int k = k0 + ((lane >> 4) << 3);
    if (i < nrows) return __builtin_bit_cast(bf16x8, *(const ushort8*)(wb + (size_t)i * ldk + k));
    ushort8 z = {0, 0, 0, 0, 0, 0, 0, 0};
    return __builtin_bit_cast(bf16x8, z);
}
// B-fragment from swizzled LDS: buf[n][cd ^ ((n&7)<<2)], 4 dwords at k0
__device__ __forceinline__ bf16x8 bfrag(const unsigned int* buf, int rowstride_dw,
                                        int n, int k0) {
    int cd = (k0 >> 1) ^ ((n & 7) << 2);
    uint4v v = *(const uint4v*)(buf + n * rowstride_dw + cd);
    return __builtin_bit_cast(bf16x8, v);
}

template <bool BF16W>
__global__ __launch_bounds__(256) void mlp_kernel(
    const float* __restrict__ pf,
    const float* __restrict__ w0, const float* __restrict__ b0_,
    const float* __restrict__ w1, const float* __restrict__ b1,
    const float* __restrict__ w2, const float* __restrict__ b2,
    const unsigned short* __restrict__ wb,
    float* __restrict__ out0) {
    __shared__ unsigned int Xs[64 * 128];   // X  [n=64][c=256] bf16, swizzled (32KB)
    __shared__ unsigned int Y0s[64 * 64];   // Y0 [n][m=128] bf16 (16KB); Y1 aliased in

    const int t    = threadIdx.x;
    const int lane = t & 63;
    const int wave = t >> 6;
    const int bid  = blockIdx.x;
    const int b    = bid / NTILE;
    const int tile = bid - b * NTILE;
    const int n0   = tile * 64;

    // ---- stage X: widened n-quad loads (16 x dwordx4 instead of 64 scalar) ----
    // thread (q = t&15, cg = t>>4): rows 4q..4q+3, channel-pairs c2 = cg + 16*it.
    {
        const int q  = t & 15;
        const int cg = t >> 4;
        const int nb = n0 + 4 * q;
        const bool vec = (nb + 3) < N_;     // full quad in range (all tiles but last)
        const float* pfb = pf + (size_t)b * C_ * N_;
#pragma unroll
        for (int it = 0; it < 8; it++) {
            int c2 = cg + 16 * it;          // c-pair 0..127
            const float* pA = pfb + (size_t)(2 * c2) * N_;
            f32x4 A, Bv;
            if (vec) {
                A  = *(const f32x4*)(pA + nb);        // channel 2*c2,   4 consecutive n
                Bv = *(const f32x4*)(pA + nb + N_);   // channel 2*c2+1
            } else {                        // tail tile: per-row clamped scalar loads
#pragma unroll
                for (int dn = 0; dn < 4; dn++) {
                    int nn = min(nb + dn, N_ - 1);    // dup rows masked at C-write
                    A[dn]  = pA[nn];
                    Bv[dn] = pA[nn + N_];
                }
            }
#pragma unroll
            for (int dn = 0; dn < 4; dn++) {
                int row = 4 * q + dn;
                Xs[row * 128 + (c2 ^ ((row & 7) << 2))] = pack2(A[dn], Bv[dn]);
            }
        }
    }

    // ---- layer 1 A preload ----
    bf16x8 a1[2][8];
#pragma unroll
    for (int mt = 0; mt < 2; mt++)
#pragma unroll
        for (int ks = 0; ks < 8; ks++)
            a1[mt][ks] = BF16W ? afrag_bf(wb, 256, (wave * 2 + mt) * 16, ks * 32, lane, 1 << 30)
                               : afrag_f32(w0, 256, (wave * 2 + mt) * 16, ks * 32, lane, 1 << 30);

    __syncthreads();

    const int cl = lane & 15;
    const int rh = lane >> 4;
    const int kq = rh << 3;

    // ---- layer 1: Y0[128,64] = leaky(W0 @ X + b0) ----
    f32x4 acc1[2][4] = {};
#pragma unroll
    for (int ks = 0; ks < 8; ks++) {
        bf16x8 bx[4];
#pragma unroll
        for (int nt = 0; nt < 4; nt++)
            bx[nt] = bfrag(Xs, 128, nt * 16 + cl, ks * 32 + kq);
#pragma unroll
        for (int mt = 0; mt < 2; mt++)
#pragma unroll
            for (int nt = 0; nt < 4; nt++)
                acc1[mt][nt] = __builtin_amdgcn_mfma_f32_16x16x32_bf16(
                    a1[mt][ks], bx[nt], acc1[mt][nt], 0, 0, 0);
    }

#pragma unroll
    for (int mt = 0; mt < 2; mt++) {
        int m0 = (wave * 2 + mt) * 16 + (rh << 2);
        f32x4 bias = *(const f32x4*)(b0_ + m0);
#pragma unroll
        for (int nt = 0; nt < 4; nt++) {
            int nn = nt * 16 + cl;
            float v0 = leaky(acc1[mt][nt][0] + bias[0]);
            float v1 = leaky(acc1[mt][nt][1] + bias[1]);
            float v2 = leaky(acc1[mt][nt][2] + bias[2]);
            float v3 = leaky(acc1[mt][nt][3] + bias[3]);
            int md = (m0 >> 1) ^ ((nn & 7) << 2);
            uint2v pk; pk[0] = pack2(v0, v1); pk[1] = pack2(v2, v3);
            *(uint2v*)(Y0s + nn * 64 + md) = pk;
        }
    }

    // ---- layer 2 A preload: K = 384 = [Y0(128) | X(256)] ----
    bf16x8 a2[12];
#pragma unroll
    for (int ks = 0; ks < 12; ks++)
        a2[ks] = BF16W ? afrag_bf(wb + WB1_OFF, 384, wave * 16, ks * 32, lane, 1 << 30)
                       : afrag_f32(w1, 384, wave * 16, ks * 32, lane, 1 << 30);

    __syncthreads();

    f32x4 acc2[4] = {};
#pragma unroll
    for (int ks = 0; ks < 12; ks++) {
#pragma unroll
        for (int nt = 0; nt < 4; nt++) {
            bf16x8 bx = (ks < 4) ? bfrag(Y0s, 64, nt * 16 + cl, ks * 32 + kq)
                                 : bfrag(Xs, 128, nt * 16 + cl, (ks - 4) * 32 + kq);
            acc2[nt] = __builtin_amdgcn_mfma_f32_16x16x32_bf16(a2[ks], bx, acc2[nt], 0, 0, 0);
        }
    }

    // layer 3 A preload (W2 zero-padded to 16 rows); K = 320 = [Y1(64) | X(256)]
    bf16x8 a3[10];
#pragma unroll
    for (int ks = 0; ks < 10; ks++)
        a3[ks] = BF16W ? afrag_bf(wb + WB2_OFF, 320, 0, ks * 32, lane, 5)
                       : afrag_f32(w2, 320, 0, ks * 32, lane, 5);

    __syncthreads();   // all waves done READING Y0s before Y1 overwrites it

    // ---- epilogue 2 -> Y1 (aliases Y0s) ----
    {
        int m0 = wave * 16 + (rh << 2);
        f32x4 bias = *(const f32x4*)(b1 + m0);
#pragma unroll
        for (int nt = 0; nt < 4; nt++) {
            int nn = nt * 16 + cl;
            float v0 = leaky(acc2[nt][0] + bias[0]);
            float v1 = leaky(acc2[nt][1] + bias[1]);
            float v2 = leaky(acc2[nt][2] + bias[2]);
            float v3 = leaky(acc2[nt][3] + bias[3]);
            int md = (m0 >> 1) ^ ((nn & 7) << 2);
            uint2v pk; pk[0] = pack2(v0, v1); pk[1] = pack2(v2, v3);
            *(uint2v*)(Y0s + nn * 32 + md) = pk;   // Y1 layout: [n][32 dwords]
        }
    }

    __syncthreads();

    // ---- layer 3: each wave owns one 16-col N-tile ----
    {
        int nn = wave * 16 + cl;
        f32x4 acc3 = {};
#pragma unroll
        for (int ks = 0; ks < 10; ks++) {
            bf16x8 bx = (ks < 2) ? bfrag(Y0s, 32, nn, ks * 32 + kq)
                                 : bfrag(Xs, 128, nn, (ks - 2) * 32 + kq);
            acc3 = __builtin_amdgcn_mfma_f32_16x16x32_bf16(a3[ks], bx, acc3, 0, 0, 0);
        }
        int gn2 = n0 + nn;
        if (gn2 < N_) {
#pragma unroll
            for (int r2 = 0; r2 < 4; r2++) {
                int m = (rh << 2) + r2;
                if (m < 5) {
                    float v = acc3[r2] + b2[m];
                    v = v > 0.f ? v : 0.f;   // final relu
                    out0[((size_t)b * 5 + m) * N_ + gn2] = v;
                }
            }
        }
    }
}

extern "C" void kernel_launch(void* const* d_in, const int* in_sizes, int n_in,
                              void* d_out, int out_size, void* d_ws, size_t ws_size,
                              hipStream_t stream) {
    const float* points = (const float*)d_in[0];
    const float* im     = (const float*)d_in[1];
    const float* w0     = (const float*)d_in[2];
    const float* b0     = (const float*)d_in[3];
    const float* w1     = (const float*)d_in[4];
    const float* b1     = (const float*)d_in[5];
    const float* w2     = (const float*)d_in[6];
    const float* b2     = (const float*)d_in[7];
    float* out0 = (float*)d_out;                   // mesh_align_feat [64][5*6890]
    float* out1 = out0 + (size_t)B_ * 5 * N_;      // point_feat      [64][256][6890]

    const size_t WBYTES = (size_t)WTOT * 2;
    const bool wok = (d_ws != nullptr) && (ws_size >= WBYTES);
    unsigned short* wb = (unsigned short*)d_ws;

    if (wok) {
        hipLaunchKernelGGL(wconv_kernel, dim3((WTOT + 255) / 256), dim3(256), 0, stream,
                           w0, w1, w2, wb);
    }
    hipLaunchKernelGGL(gather_kernel, dim3(B_ * 64), dim3(512), 0, stream,
                       points, im, out1);
    if (wok) {
        hipLaunchKernelGGL(mlp_kernel<true>, dim3(B_ * NTILE), dim3(256), 0, stream,
                           out1, w0, b0, w1, b1, w2, b2, wb, out0);
    } else {
        hipLaunchKernelGGL(mlp_kernel<false>, dim3(B_ * NTILE), dim3(256), 0, stream,
                           out1, w0, b0, w1, b1, w2, b2, (const unsigned short*)nullptr, out0);
    }
}